// Round 17
// baseline (505.642 us; speedup 1.0000x reference)
//
#include <hip/hip_runtime.h>
#include <math.h>

#define NN 50000
#define EE 800000
#define DD 32
#define BSTR 64    // bucket stride (max degree ~45 at Poisson(16); +8 pad fits)
#define NPART 8    // node-range partitions, mapped to XCDs via blockIdx&7
#define CPB 128    // edge chunks per partition (grid = 8*128 = 1024 blocks)

typedef float v2f __attribute__((ext_vector_type(2)));

// ---------------- setup kernels ----------------

__global__ __launch_bounds__(256) void k_zero(float* p, int count){
  int i = blockIdx.x*256 + threadIdx.x;
  if (i < count) p[i] = 0.f;
}

// XCD-partitioned one-pass CSR build (R16-proven: cut write-amp 51->~12 MB).
__global__ __launch_bounds__(256) void k_fillcsr(const int* __restrict__ node_in,
                                                 const int* __restrict__ node_out,
                                                 const float* __restrict__ ew,
                                                 int* __restrict__ cursor,
                                                 int2* __restrict__ csr){
  int part  = blockIdx.x & (NPART-1);
  int group = blockIdx.x >> 3;
  const int per = (EE + CPB - 1) / CPB;   // 6250
  int e0 = group * per;
  int e1 = (e0 + per < EE) ? (e0 + per) : EE;
  unsigned lo = (unsigned)part * 6250u;
  unsigned hi = lo + 6250u;
  for (int e = e0 + threadIdx.x; e < e1; e += 256){
    unsigned o = (unsigned)node_out[e];
    if (o >= lo && o < hi){
      int pos = atomicAdd(&cursor[o], 1);
      int2 v; v.x = node_in[e]; v.y = __float_as_int(ew[e]);
      csr[o*BSTR + pos] = v;
    }
  }
}

// per-node sum(w) over its bucket row + global logsum reduce + zero the
// 8-entry pad tail (k_layer's unconditional reads land in [0, deg+8)).
__global__ __launch_bounds__(256) void k_sumw(int2* __restrict__ csr,
                                              const int* __restrict__ cursor,
                                              float* __restrict__ deg_w,
                                              float* __restrict__ logsum){
  __shared__ float sf[256];
  int t = threadIdx.x; int n = blockIdx.x*256 + t;
  float s = 0.f;
  if (n < NN){
    int deg = cursor[n];
    int2* row = csr + n*BSTR;
    for (int i = 0; i < deg; ++i) s += __int_as_float(row[i].y);
    deg_w[n] = s;
    #pragma unroll
    for (int i = 0; i < 8; ++i) row[deg + i] = make_int2(0, 0);
  }
  sf[t] = (n < NN) ? logf(s + 1.f) : 0.f;
  __syncthreads();
  for (int off = 128; off > 0; off >>= 1){
    if (t < off) sf[t] += sf[t+off];
    __syncthreads();
  }
  if (t == 0) atomicAdd(logsum, sf[0]);
}

__global__ __launch_bounds__(256) void k_scales(const float* __restrict__ deg_w,
                                                const float* __restrict__ logsum,
                                                float* __restrict__ scale_arr,
                                                float* __restrict__ inv_arr){
  int n = blockIdx.x*256 + threadIdx.x;
  if (n < NN){
    float mean = *logsum / (float)NN;
    float s = logf(deg_w[n] + 1.f) / mean;
    scale_arr[n] = s;
    inv_arr[n]   = 1.f / fmaxf(s, 0.01f);
  }
}

// rel_input per layer (6x32) and query-part of final MLP (64)
__global__ __launch_bounds__(256) void k_prep(const float* __restrict__ qw,
                                              const float* __restrict__ rel_W,
                                              const float* __restrict__ rel_b,
                                              const float* __restrict__ W1,
                                              const float* __restrict__ b1,
                                              float* __restrict__ rel6,
                                              float* __restrict__ qc){
  int t = threadIdx.x;
  if (t < 192){
    int l = t >> 5, j = t & 31;
    float s = rel_b[t];
    for (int d = 0; d < 32; ++d) s += qw[d] * rel_W[l*1024 + d*32 + j];
    rel6[t] = s;
  } else if (t < 256){
    int j = t - 192;
    float s = b1[j];
    for (int k = 0; k < 32; ++k) s += qw[k] * W1[(32+k)*64 + j];
    qc[j] = s;
  }
}

__global__ __launch_bounds__(256) void k_init_h(const int* __restrict__ hidx,
                                                float* __restrict__ h){
  int i = blockIdx.x*256 + threadIdx.x;
  int hv = *hidx;
  if (i < NN*DD) h[i] = ((i >> 5) == hv) ? 0.f : 100.f;
}

// t[n] = dot(h[n], rel_layer5) for msg_score
__global__ __launch_bounds__(256) void k_dot(const float* __restrict__ h,
                                             const float* __restrict__ rel6,
                                             float* __restrict__ tdot){
  int n0 = blockIdx.x*256 + threadIdx.x;
  int n = (n0 < NN) ? n0 : NN-1;
  const float* relr = rel6 + 5*32;
  float s = 0.f;
  #pragma unroll
  for (int d = 0; d < 32; ++d) s += h[n*32 + d] * relr[d];
  if (n0 < NN) tdot[n0] = s;
}

// ---------------- fused per-layer kernel ----------------
// Block = 64 nodes, 512 threads = 8 waves. Phase 1: one 8-lane group per
// node, UNROLL-8 issue-then-wait (8 independent h dwordx4 + 8 csr prefetch
// per batch; exposed latency per edge ~600/8 cyc). No cross-iteration
// rotation of gather values (R7/R14 lesson: rotation + VGPR cost beats the
// latency saved; issue-many-then-wait wins on this compiler). Tail: up to 7
// h-gathers issued UNCONDITIONALLY (pad csr entries are zeroed -> src=0 ->
// h row 0, valid address), then guarded ACCs -- one wait, no serial chain.
// launch_bounds(512,4): VGPR cap 128 for the ~90-reg batch.
// Phase 2: packed fp32 j-split, wave-uniform W -> s_load; x from own h row.
template<bool PRED>
__global__ __launch_bounds__(512, 4) void k_layer(const float* __restrict__ h,
                                               const float* __restrict__ rel6,
                                               const int* __restrict__ cursor,
                                               const int2* __restrict__ csr,
                                               const int* __restrict__ hidx,
                                               const float* __restrict__ tdot,
                                               const float* __restrict__ lin_W,
                                               const float* __restrict__ lin_b,
                                               const float* __restrict__ scale_arr,
                                               const float* __restrict__ inv_arr,
                                               float* __restrict__ h_next,
                                               float* __restrict__ pred_out,
                                               int l){
  __shared__ float sh[128*65];
  int tid = threadIdx.x;
  int base = blockIdx.x * 64;
  int hv0 = *hidx;

  // ---- phase 1: aggregation (one 8-lane group per node, unroll-8) ----
  {
    int nl   = tid >> 3;     // group = node index in block, 0..63
    int quad = tid & 7;      // dims quad*4..+3
    float4 r4 = ((const float4*)(rel6 + l*32))[quad];
    int n0 = base + nl;
    bool valid = n0 < NN;
    int n = valid ? n0 : NN-1;
    int deg = cursor[n];
    int s0 = n*BSTR, s1 = s0 + deg;
    float S10=0.f,S11=0.f,S12=0.f,S13=0.f;
    float S20=0.f,S21=0.f,S22=0.f,S23=0.f;
    float M0=-INFINITY,M1=-INFINITY,M2=-INFINITY,M3=-INFINITY;
    float m0=INFINITY,m1=INFINITY,m2=INFINITY,m3=INFINITY;
    float best=-INFINITY; int bi=NN;

#define H4(C) (((const float4*)(h + (C).x*32))[quad])
#define ACC1(C, A, T) { \
    float w = __int_as_float(C.y); \
    float p0=w*A.x, p1=w*A.y, p2=w*A.z, p3=w*A.w; \
    S10+=p0; S11+=p1; S12+=p2; S13+=p3; \
    S20+=p0*A.x; S21+=p1*A.y; S22+=p2*A.z; S23+=p3*A.w; \
    M0=fmaxf(M0,p0); M1=fmaxf(M1,p1); M2=fmaxf(M2,p2); M3=fmaxf(M3,p3); \
    m0=fminf(m0,p0); m1=fminf(m1,p1); m2=fminf(m2,p2); m3=fminf(m3,p3); \
    if (PRED){ \
      float sv = w*T; \
      if (sv > best){ best = sv; bi = C.x; } \
      else if (sv == best && C.x < bi) bi = C.x; \
    } }

    // prologue reads are unconditional: pad tail [deg, deg+8) is zeroed
    int2 c0 = csr[s0+0], c1 = csr[s0+1], c2 = csr[s0+2], c3 = csr[s0+3];
    int2 c4 = csr[s0+4], c5 = csr[s0+5], c6 = csr[s0+6], c7 = csr[s0+7];
    int e = s0;
    for (; e + 8 <= s1; e += 8){
      // 8 independent gathers in flight, one wait
      float4 a0 = H4(c0), a1 = H4(c1), a2 = H4(c2), a3 = H4(c3);
      float4 a4 = H4(c4), a5 = H4(c5), a6 = H4(c6), a7 = H4(c7);
      float t0=0.f,t1=0.f,t2=0.f,t3=0.f,t4=0.f,t5=0.f,t6=0.f,t7=0.f;
      if (PRED){
        t0=tdot[c0.x]; t1=tdot[c1.x]; t2=tdot[c2.x]; t3=tdot[c3.x];
        t4=tdot[c4.x]; t5=tdot[c5.x]; t6=tdot[c6.x]; t7=tdot[c7.x];
      }
      // prefetch next batch's csr (pad covers reads to s1+7)
      int2 n0_ = csr[e+8],  n1_ = csr[e+9],  n2_ = csr[e+10], n3_ = csr[e+11];
      int2 n4_ = csr[e+12], n5_ = csr[e+13], n6_ = csr[e+14], n7_ = csr[e+15];
      ACC1(c0, a0, t0) ACC1(c1, a1, t1) ACC1(c2, a2, t2) ACC1(c3, a3, t3)
      ACC1(c4, a4, t4) ACC1(c5, a5, t5) ACC1(c6, a6, t6) ACC1(c7, a7, t7)
      c0=n0_; c1=n1_; c2=n2_; c3=n3_; c4=n4_; c5=n5_; c6=n6_; c7=n7_;
    }
    // tail 0..7 edges: issue all 7 gathers unconditionally (pad src=0 ->
    // h row 0, valid), then guarded accumulation. One wait.
    int rem = s1 - e;
    if (rem > 0){
      float4 a0 = H4(c0), a1 = H4(c1), a2 = H4(c2), a3 = H4(c3);
      float4 a4 = H4(c4), a5 = H4(c5), a6 = H4(c6);
      float t0=0.f,t1=0.f,t2=0.f,t3=0.f,t4=0.f,t5=0.f,t6=0.f;
      if (PRED){
        t0=tdot[c0.x]; t1=tdot[c1.x]; t2=tdot[c2.x]; t3=tdot[c3.x];
        t4=tdot[c4.x]; t5=tdot[c5.x]; t6=tdot[c6.x];
      }
      ACC1(c0, a0, t0)
      if (rem > 1) ACC1(c1, a1, t1)
      if (rem > 2) ACC1(c2, a2, t2)
      if (rem > 3) ACC1(c3, a3, t3)
      if (rem > 4) ACC1(c4, a4, t4)
      if (rem > 5) ACC1(c5, a5, t5)
      if (rem > 6) ACC1(c6, a6, t6)
    }
#undef ACC1
#undef H4

    // finalize (no cross-lane reduction needed)
    float bnd = (n == hv0) ? 0.f : 100.f;
    float cntf = (float)(deg + 1);
#define FIN(cc, rc, S1c, S2c, Mc, mc) { \
    float mxv, mnv; \
    if (deg > 0){ \
      float em = (rc >= 0.f) ? rc*Mc : rc*mc; \
      float en = (rc >= 0.f) ? rc*mc : rc*Mc; \
      mxv = fmaxf(em, bnd); mnv = fminf(en, bnd); \
    } else { mxv = bnd; mnv = bnd; } \
    float meanv = (rc*S1c + bnd) / cntf; \
    float sq    = (rc*rc*S2c + bnd*bnd) / cntf; \
    float sdv   = sqrtf(fmaxf(sq - meanv*meanv, 1e-6f)); \
    int d = quad*4 + cc; \
    sh[(d*4+0)*65 + nl] = meanv; \
    sh[(d*4+1)*65 + nl] = mxv; \
    sh[(d*4+2)*65 + nl] = mnv; \
    sh[(d*4+3)*65 + nl] = sdv; }
    FIN(0, r4.x, S10, S20, M0, m0)
    FIN(1, r4.y, S11, S21, M1, m1)
    FIN(2, r4.z, S12, S22, M2, m2)
    FIN(3, r4.w, S13, S23, M3, m3)
#undef FIN
    if (PRED && valid && quad == 0){
      float ss = (n == hv0) ? 0.f : 3200.f;   // boundary self-loop row sum, w=1
      if (ss > best){ best = ss; bi = n; }
      else if (ss == best && n < bi) bi = n;
      pred_out[n] = (float)bi;
    }
  }
  __syncthreads();

  // ---- phase 2: linear (8 waves, wave w -> j0 = w*4; node = lane) ----
  // packed fp32 (v_pk_fma_f32); x from own h row (8 dwordx4, one wait)
  {
    const float* Wl = lin_W + (size_t)l * 13312;   // 416*32
    int lane = tid & 63;
    int j0 = __builtin_amdgcn_readfirstlane((tid >> 6) * 4);  // 0,4,...,28
    int n0 = base + lane;
    int n = (n0 < NN) ? n0 : NN-1;
    float sc = scale_arr[n], iv = inv_arr[n];
    const float4* hr = (const float4*)(h + (size_t)n*32);
    float4 x0=hr[0],x1=hr[1],x2=hr[2],x3=hr[3],x4=hr[4],x5=hr[5],x6=hr[6],x7=hr[7];
    v2f a01, a23;
    a01[0] = lin_b[l*32 + j0 + 0]; a01[1] = lin_b[l*32 + j0 + 1];
    a23[0] = lin_b[l*32 + j0 + 2]; a23[1] = lin_b[l*32 + j0 + 3];

#define KONE(XV, K) { \
    v2f xv2; xv2[0] = XV; xv2[1] = XV; \
    const v2f* wr2 = (const v2f*)(Wl + (K)*32 + j0); \
    a01 += xv2 * wr2[0]; \
    a23 += xv2 * wr2[1]; }
#define KQ(X, KB) KONE(X.x, KB+0) KONE(X.y, KB+1) KONE(X.z, KB+2) KONE(X.w, KB+3)
    KQ(x0, 0) KQ(x1, 4) KQ(x2, 8) KQ(x3, 12)
    KQ(x4, 16) KQ(x5, 20) KQ(x6, 24) KQ(x7, 28)
#undef KQ
#undef KONE

    for (int kp = 0; kp < 128; ++kp){
      float f = sh[kp*65 + lane];
      int d = kp >> 2, c = kp & 3;
      const v2f* w2 = (const v2f*)(Wl + (32 + d*12 + c*3)*32 + j0);
      float f1 = f*sc, f2 = f*iv;
      v2f fv;  fv[0]=f;  fv[1]=f;
      v2f f1v; f1v[0]=f1; f1v[1]=f1;
      v2f f2v; f2v[0]=f2; f2v[1]=f2;
      // rows are 32 floats = 16 v2f apart
      a01 += fv*w2[0] + f1v*w2[16] + f2v*w2[32];
      a23 += fv*w2[1] + f1v*w2[17] + f2v*w2[33];
    }

    if (n0 < NN){
      float vs[4] = { a01[0], a01[1], a23[0], a23[1] };
      #pragma unroll
      for (int j = 0; j < 4; ++j)
        h_next[n0*32 + j0 + j] = fmaxf(vs[j], 0.f);
    }
  }
}

// ---------------- final MLP (reads h row-major) ----------------
__global__ __launch_bounds__(256) void k_mlp(const float* __restrict__ h,
                                             const float* __restrict__ qc,
                                             const float* __restrict__ W1,
                                             const float* __restrict__ W2,
                                             const float* __restrict__ b2,
                                             float* __restrict__ out_score){
  int n0 = blockIdx.x*256 + threadIdx.x;
  int n = (n0 < NN) ? n0 : NN-1;
  float xr[32];
  const float4* hr = (const float4*)(h + (size_t)n*32);
  #pragma unroll
  for (int q = 0; q < 8; ++q){
    float4 x = hr[q];
    xr[q*4+0]=x.x; xr[q*4+1]=x.y; xr[q*4+2]=x.z; xr[q*4+3]=x.w;
  }
  float acc[64];
  #pragma unroll
  for (int j = 0; j < 64; ++j) acc[j] = qc[j];
  #pragma unroll
  for (int k = 0; k < 32; ++k){
    float xv = xr[k];
    const float* wr = W1 + k*64;
    #pragma unroll
    for (int j = 0; j < 64; ++j) acc[j] += xv * wr[j];
  }
  float s = b2[0];
  #pragma unroll
  for (int j = 0; j < 64; ++j) s += fmaxf(acc[j], 0.f) * W2[j];
  if (n0 < NN) out_score[n0] = s;
}

// ---------------- host launch ----------------
extern "C" void kernel_launch(void* const* d_in, const int* in_sizes, int n_in,
                              void* d_out, int out_size, void* d_ws, size_t ws_size,
                              hipStream_t stream){
  const int*   node_in  = (const int*)d_in[0];
  const int*   node_out = (const int*)d_in[1];
  const float* ew       = (const float*)d_in[2];
  const int*   hidx     = (const int*)d_in[3];
  const float* qw       = (const float*)d_in[4];
  const float* rel_W    = (const float*)d_in[5];
  const float* rel_b    = (const float*)d_in[6];
  const float* lin_W    = (const float*)d_in[7];
  const float* lin_b    = (const float*)d_in[8];
  const float* W1       = (const float*)d_in[9];
  const float* b1       = (const float*)d_in[10];
  const float* W2       = (const float*)d_in[11];
  const float* b2       = (const float*)d_in[12];
  float* out_score = (float*)d_out;
  float* out_pred  = out_score + NN;

  char* w = (char*)d_ws;
  size_t off = 0;
  auto take = [&](size_t bytes)->char*{
    char* p = w + off;
    off = (off + bytes + 255) & ~(size_t)255;
    return p;
  };
  size_t bucket_elems = (size_t)NN * BSTR;            // int2 entries
  int2*  csr      = (int2*)take(bucket_elems*8);
  // contiguous zero block: cursor | deg_w | logsum
  char*  zb       = take((size_t)NN*4 + (size_t)NN*4 + 256);
  int*   cursor   = (int*)zb;
  float* deg_w    = (float*)(cursor + NN);
  float* logsum   = (float*)(deg_w + NN);
  int zc = NN + NN + 64;

  float* rel6      = (float*)take(192*4);
  float* qc        = (float*)take(64*4);
  float* scale_arr = (float*)take((size_t)NN*4);
  float* inv_arr   = (float*)take((size_t)NN*4);
  float* tdot      = (float*)take((size_t)NN*4);
  float* h_a       = (float*)take((size_t)NN*32*4);
  float* h_b       = (float*)take((size_t)NN*32*4);

  int nb  = (NN + 255) / 256;   // 196
  int nlb = (NN + 63) / 64;     // 782
  k_zero   <<<(zc+255)/256, 256, 0, stream>>>((float*)zb, zc);
  k_fillcsr<<<NPART*CPB, 256, 0, stream>>>(node_in, node_out, ew, cursor, csr);
  k_sumw   <<<nb, 256, 0, stream>>>(csr, cursor, deg_w, logsum);
  k_scales <<<nb, 256, 0, stream>>>(deg_w, logsum, scale_arr, inv_arr);
  k_prep   <<<1, 256, 0, stream>>>(qw, rel_W, rel_b, W1, b1, rel6, qc);
  k_init_h <<<(NN*DD+255)/256, 256, 0, stream>>>(hidx, h_a);

  float* hc = h_a;
  float* hn = h_b;
  for (int l = 0; l < 6; ++l){
    if (l == 5){
      k_dot<<<nb, 256, 0, stream>>>(hc, rel6, tdot);
      k_layer<true><<<nlb, 512, 0, stream>>>(hc, rel6, cursor, csr, hidx, tdot,
                                             lin_W, lin_b, scale_arr, inv_arr,
                                             hn, out_pred, l);
    } else {
      k_layer<false><<<nlb, 512, 0, stream>>>(hc, rel6, cursor, csr, hidx, tdot,
                                              lin_W, lin_b, scale_arr, inv_arr,
                                              hn, out_pred, l);
    }
    float* t1 = hc; hc = hn; hn = t1;
  }
  k_mlp<<<nb, 256, 0, stream>>>(hc, qc, W1, W2, b2, out_score);
}

// Round 18
// 461.146 us; speedup vs baseline: 1.0965x; 1.0965x over previous
//
#include <hip/hip_runtime.h>
#include <math.h>

#define NN 50000
#define EE 800000
#define DD 32
#define BSTR 64    // bucket stride (max degree ~45 at Poisson(16); +8 pad fits)
#define NPART 8    // node-range partitions, mapped to XCDs via blockIdx&7
#define CPB 128    // edge chunks per partition (grid = 8*128 = 1024 blocks)

typedef float v2f __attribute__((ext_vector_type(2)));

// ---------------- setup kernels ----------------

__global__ __launch_bounds__(256) void k_zero(float* p, int count){
  int i = blockIdx.x*256 + threadIdx.x;
  if (i < count) p[i] = 0.f;
}

// XCD-partitioned one-pass CSR build (R16-proven: cut write-amp 51->~12 MB).
__global__ __launch_bounds__(256) void k_fillcsr(const int* __restrict__ node_in,
                                                 const int* __restrict__ node_out,
                                                 const float* __restrict__ ew,
                                                 int* __restrict__ cursor,
                                                 int2* __restrict__ csr){
  int part  = blockIdx.x & (NPART-1);
  int group = blockIdx.x >> 3;
  const int per = (EE + CPB - 1) / CPB;   // 6250
  int e0 = group * per;
  int e1 = (e0 + per < EE) ? (e0 + per) : EE;
  unsigned lo = (unsigned)part * 6250u;
  unsigned hi = lo + 6250u;
  for (int e = e0 + threadIdx.x; e < e1; e += 256){
    unsigned o = (unsigned)node_out[e];
    if (o >= lo && o < hi){
      int pos = atomicAdd(&cursor[o], 1);
      int2 v; v.x = node_in[e]; v.y = __float_as_int(ew[e]);
      csr[o*BSTR + pos] = v;
    }
  }
}

// per-node sum(w) over its bucket row + global logsum reduce + zero the
// 8-entry pad tail (k_layer's unconditional reads land in [0, deg+8)).
__global__ __launch_bounds__(256) void k_sumw(int2* __restrict__ csr,
                                              const int* __restrict__ cursor,
                                              float* __restrict__ deg_w,
                                              float* __restrict__ logsum){
  __shared__ float sf[256];
  int t = threadIdx.x; int n = blockIdx.x*256 + t;
  float s = 0.f;
  if (n < NN){
    int deg = cursor[n];
    int2* row = csr + n*BSTR;
    for (int i = 0; i < deg; ++i) s += __int_as_float(row[i].y);
    deg_w[n] = s;
    #pragma unroll
    for (int i = 0; i < 8; ++i) row[deg + i] = make_int2(0, 0);
  }
  sf[t] = (n < NN) ? logf(s + 1.f) : 0.f;
  __syncthreads();
  for (int off = 128; off > 0; off >>= 1){
    if (t < off) sf[t] += sf[t+off];
    __syncthreads();
  }
  if (t == 0) atomicAdd(logsum, sf[0]);
}

// rel_input per layer (6x32) and query-part of final MLP (64)
__global__ __launch_bounds__(256) void k_prep(const float* __restrict__ qw,
                                              const float* __restrict__ rel_W,
                                              const float* __restrict__ rel_b,
                                              const float* __restrict__ W1,
                                              const float* __restrict__ b1,
                                              float* __restrict__ rel6,
                                              float* __restrict__ qc){
  int t = threadIdx.x;
  if (t < 192){
    int l = t >> 5, j = t & 31;
    float s = rel_b[t];
    for (int d = 0; d < 32; ++d) s += qw[d] * rel_W[l*1024 + d*32 + j];
    rel6[t] = s;
  } else if (t < 256){
    int j = t - 192;
    float s = b1[j];
    for (int k = 0; k < 32; ++k) s += qw[k] * W1[(32+k)*64 + j];
    qc[j] = s;
  }
}

__global__ __launch_bounds__(256) void k_init_h(const int* __restrict__ hidx,
                                                float* __restrict__ h){
  int i = blockIdx.x*256 + threadIdx.x;
  int hv = *hidx;
  if (i < NN*DD) h[i] = ((i >> 5) == hv) ? 0.f : 100.f;
}

// t[n] = dot(h[n], rel_layer5) for msg_score
__global__ __launch_bounds__(256) void k_dot(const float* __restrict__ h,
                                             const float* __restrict__ rel6,
                                             float* __restrict__ tdot){
  int n0 = blockIdx.x*256 + threadIdx.x;
  int n = (n0 < NN) ? n0 : NN-1;
  const float* relr = rel6 + 5*32;
  float s = 0.f;
  #pragma unroll
  for (int d = 0; d < 32; ++d) s += h[n*32 + d] * relr[d];
  if (n0 < NN) tdot[n0] = s;
}

// ---------------- fused per-layer kernel ----------------
// Block = 64 nodes, 512 threads = 8 waves. Phase 1 = R16's proven unroll-4:
// issue 4 independent h dwordx4 + 4 csr prefetches, ONE wait per batch.
// (Tested unroll-2/4/8 + two explicit pipelines: unroll-4 at (512,6) wins --
// 8 blows tails/VGPR, explicit rotation costs more than the latency saved.)
// CSR = fixed-stride buckets: s0 = n*64, deg = cursor[n]; tail [deg,deg+8)
// zeroed by k_sumw so unconditional reads are safe.
// Phase 2: packed fp32 j-split, wave-uniform W -> s_load; x from own h row;
// scale/inv computed inline from deg_w+logsum (k_scales kernel deleted;
// formula order matches reference: mean=logsum/N, s=log(dw+1)/mean).
template<bool PRED>
__global__ __launch_bounds__(512, 6) void k_layer(const float* __restrict__ h,
                                               const float* __restrict__ rel6,
                                               const int* __restrict__ cursor,
                                               const int2* __restrict__ csr,
                                               const int* __restrict__ hidx,
                                               const float* __restrict__ tdot,
                                               const float* __restrict__ lin_W,
                                               const float* __restrict__ lin_b,
                                               const float* __restrict__ deg_w,
                                               const float* __restrict__ logsum,
                                               float* __restrict__ h_next,
                                               float* __restrict__ pred_out,
                                               int l){
  __shared__ float sh[128*65];
  int tid = threadIdx.x;
  int base = blockIdx.x * 64;
  int hv0 = *hidx;

  // ---- phase 1: aggregation (one 8-lane group per node, unroll-4) ----
  {
    int nl   = tid >> 3;     // group = node index in block, 0..63
    int quad = tid & 7;      // dims quad*4..+3
    float4 r4 = ((const float4*)(rel6 + l*32))[quad];
    int n0 = base + nl;
    bool valid = n0 < NN;
    int n = valid ? n0 : NN-1;
    int deg = cursor[n];
    int s0 = n*BSTR, s1 = s0 + deg;
    float S10=0.f,S11=0.f,S12=0.f,S13=0.f;
    float S20=0.f,S21=0.f,S22=0.f,S23=0.f;
    float M0=-INFINITY,M1=-INFINITY,M2=-INFINITY,M3=-INFINITY;
    float m0=INFINITY,m1=INFINITY,m2=INFINITY,m3=INFINITY;
    float best=-INFINITY; int bi=NN;

#define ACC1(C, A, T) { \
    float w = __int_as_float(C.y); \
    float p0=w*A.x, p1=w*A.y, p2=w*A.z, p3=w*A.w; \
    S10+=p0; S11+=p1; S12+=p2; S13+=p3; \
    S20+=p0*A.x; S21+=p1*A.y; S22+=p2*A.z; S23+=p3*A.w; \
    M0=fmaxf(M0,p0); M1=fmaxf(M1,p1); M2=fmaxf(M2,p2); M3=fmaxf(M3,p3); \
    m0=fminf(m0,p0); m1=fminf(m1,p1); m2=fminf(m2,p2); m3=fminf(m3,p3); \
    if (PRED){ \
      float sv = w*T; \
      if (sv > best){ best = sv; bi = C.x; } \
      else if (sv == best && C.x < bi) bi = C.x; \
    } }

    // prologue reads are unconditional: pad tail [deg, deg+8) is zeroed
    int2 cA = csr[s0],   cB = csr[s0+1], cC = csr[s0+2], cD = csr[s0+3];
    int e = s0;
    for (; e + 4 <= s1; e += 4){
      float4 a  = ((const float4*)(h + cA.x*32))[quad];
      float4 b  = ((const float4*)(h + cB.x*32))[quad];
      float4 c4 = ((const float4*)(h + cC.x*32))[quad];
      float4 d4 = ((const float4*)(h + cD.x*32))[quad];
      float tA=0.f, tB=0.f, tC=0.f, tD=0.f;
      if (PRED){ tA = tdot[cA.x]; tB = tdot[cB.x]; tC = tdot[cC.x]; tD = tdot[cD.x]; }
      int2 nA = csr[e+4], nB = csr[e+5], nC = csr[e+6], nD = csr[e+7];
      ACC1(cA, a, tA)
      ACC1(cB, b, tB)
      ACC1(cC, c4, tC)
      ACC1(cD, d4, tD)
      cA = nA; cB = nB; cC = nC; cD = nD;
    }
    // tail 0..3 edges (cA..cC hold csr[e..e+2])
    if (e < s1){
      float4 a = ((const float4*)(h + cA.x*32))[quad];
      float tA = 0.f; if (PRED) tA = tdot[cA.x];
      ACC1(cA, a, tA)
      if (e + 1 < s1){
        float4 b = ((const float4*)(h + cB.x*32))[quad];
        float tB = 0.f; if (PRED) tB = tdot[cB.x];
        ACC1(cB, b, tB)
        if (e + 2 < s1){
          float4 c4 = ((const float4*)(h + cC.x*32))[quad];
          float tC = 0.f; if (PRED) tC = tdot[cC.x];
          ACC1(cC, c4, tC)
        }
      }
    }
#undef ACC1

    // finalize (no cross-lane reduction needed)
    float bnd = (n == hv0) ? 0.f : 100.f;
    float cntf = (float)(deg + 1);
#define FIN(cc, rc, S1c, S2c, Mc, mc) { \
    float mxv, mnv; \
    if (deg > 0){ \
      float em = (rc >= 0.f) ? rc*Mc : rc*mc; \
      float en = (rc >= 0.f) ? rc*mc : rc*Mc; \
      mxv = fmaxf(em, bnd); mnv = fminf(en, bnd); \
    } else { mxv = bnd; mnv = bnd; } \
    float meanv = (rc*S1c + bnd) / cntf; \
    float sq    = (rc*rc*S2c + bnd*bnd) / cntf; \
    float sdv   = sqrtf(fmaxf(sq - meanv*meanv, 1e-6f)); \
    int d = quad*4 + cc; \
    sh[(d*4+0)*65 + nl] = meanv; \
    sh[(d*4+1)*65 + nl] = mxv; \
    sh[(d*4+2)*65 + nl] = mnv; \
    sh[(d*4+3)*65 + nl] = sdv; }
    FIN(0, r4.x, S10, S20, M0, m0)
    FIN(1, r4.y, S11, S21, M1, m1)
    FIN(2, r4.z, S12, S22, M2, m2)
    FIN(3, r4.w, S13, S23, M3, m3)
#undef FIN
    if (PRED && valid && quad == 0){
      float ss = (n == hv0) ? 0.f : 3200.f;   // boundary self-loop row sum, w=1
      if (ss > best){ best = ss; bi = n; }
      else if (ss == best && n < bi) bi = n;
      pred_out[n] = (float)bi;
    }
  }
  __syncthreads();

  // ---- phase 2: linear (8 waves, wave w -> j0 = w*4; node = lane) ----
  // packed fp32 (v_pk_fma_f32); x from own h row (8 dwordx4, one wait);
  // scale/inv inline from deg_w + logsum (reference op order).
  {
    const float* Wl = lin_W + (size_t)l * 13312;   // 416*32
    int lane = tid & 63;
    int j0 = __builtin_amdgcn_readfirstlane((tid >> 6) * 4);  // 0,4,...,28
    int n0 = base + lane;
    int n = (n0 < NN) ? n0 : NN-1;
    float mean = *logsum / (float)NN;
    float sc = logf(deg_w[n] + 1.f) / mean;
    float iv = 1.f / fmaxf(sc, 0.01f);
    const float4* hr = (const float4*)(h + (size_t)n*32);
    float4 x0=hr[0],x1=hr[1],x2=hr[2],x3=hr[3],x4=hr[4],x5=hr[5],x6=hr[6],x7=hr[7];
    v2f a01, a23;
    a01[0] = lin_b[l*32 + j0 + 0]; a01[1] = lin_b[l*32 + j0 + 1];
    a23[0] = lin_b[l*32 + j0 + 2]; a23[1] = lin_b[l*32 + j0 + 3];

#define KONE(XV, K) { \
    v2f xv2; xv2[0] = XV; xv2[1] = XV; \
    const v2f* wr2 = (const v2f*)(Wl + (K)*32 + j0); \
    a01 += xv2 * wr2[0]; \
    a23 += xv2 * wr2[1]; }
#define KQ(X, KB) KONE(X.x, KB+0) KONE(X.y, KB+1) KONE(X.z, KB+2) KONE(X.w, KB+3)
    KQ(x0, 0) KQ(x1, 4) KQ(x2, 8) KQ(x3, 12)
    KQ(x4, 16) KQ(x5, 20) KQ(x6, 24) KQ(x7, 28)
#undef KQ
#undef KONE

    for (int kp = 0; kp < 128; ++kp){
      float f = sh[kp*65 + lane];
      int d = kp >> 2, c = kp & 3;
      const v2f* w2 = (const v2f*)(Wl + (32 + d*12 + c*3)*32 + j0);
      float f1 = f*sc, f2 = f*iv;
      v2f fv;  fv[0]=f;  fv[1]=f;
      v2f f1v; f1v[0]=f1; f1v[1]=f1;
      v2f f2v; f2v[0]=f2; f2v[1]=f2;
      // rows are 32 floats = 16 v2f apart
      a01 += fv*w2[0] + f1v*w2[16] + f2v*w2[32];
      a23 += fv*w2[1] + f1v*w2[17] + f2v*w2[33];
    }

    if (n0 < NN){
      float vs[4] = { a01[0], a01[1], a23[0], a23[1] };
      #pragma unroll
      for (int j = 0; j < 4; ++j)
        h_next[n0*32 + j0 + j] = fmaxf(vs[j], 0.f);
    }
  }
}

// ---------------- final MLP (reads h row-major) ----------------
__global__ __launch_bounds__(256) void k_mlp(const float* __restrict__ h,
                                             const float* __restrict__ qc,
                                             const float* __restrict__ W1,
                                             const float* __restrict__ W2,
                                             const float* __restrict__ b2,
                                             float* __restrict__ out_score){
  int n0 = blockIdx.x*256 + threadIdx.x;
  int n = (n0 < NN) ? n0 : NN-1;
  float xr[32];
  const float4* hr = (const float4*)(h + (size_t)n*32);
  #pragma unroll
  for (int q = 0; q < 8; ++q){
    float4 x = hr[q];
    xr[q*4+0]=x.x; xr[q*4+1]=x.y; xr[q*4+2]=x.z; xr[q*4+3]=x.w;
  }
  float acc[64];
  #pragma unroll
  for (int j = 0; j < 64; ++j) acc[j] = qc[j];
  #pragma unroll
  for (int k = 0; k < 32; ++k){
    float xv = xr[k];
    const float* wr = W1 + k*64;
    #pragma unroll
    for (int j = 0; j < 64; ++j) acc[j] += xv * wr[j];
  }
  float s = b2[0];
  #pragma unroll
  for (int j = 0; j < 64; ++j) s += fmaxf(acc[j], 0.f) * W2[j];
  if (n0 < NN) out_score[n0] = s;
}

// ---------------- host launch ----------------
extern "C" void kernel_launch(void* const* d_in, const int* in_sizes, int n_in,
                              void* d_out, int out_size, void* d_ws, size_t ws_size,
                              hipStream_t stream){
  const int*   node_in  = (const int*)d_in[0];
  const int*   node_out = (const int*)d_in[1];
  const float* ew       = (const float*)d_in[2];
  const int*   hidx     = (const int*)d_in[3];
  const float* qw       = (const float*)d_in[4];
  const float* rel_W    = (const float*)d_in[5];
  const float* rel_b    = (const float*)d_in[6];
  const float* lin_W    = (const float*)d_in[7];
  const float* lin_b    = (const float*)d_in[8];
  const float* W1       = (const float*)d_in[9];
  const float* b1       = (const float*)d_in[10];
  const float* W2       = (const float*)d_in[11];
  const float* b2       = (const float*)d_in[12];
  float* out_score = (float*)d_out;
  float* out_pred  = out_score + NN;

  char* w = (char*)d_ws;
  size_t off = 0;
  auto take = [&](size_t bytes)->char*{
    char* p = w + off;
    off = (off + bytes + 255) & ~(size_t)255;
    return p;
  };
  size_t bucket_elems = (size_t)NN * BSTR;            // int2 entries
  int2*  csr      = (int2*)take(bucket_elems*8);
  // contiguous zero block: cursor | deg_w | logsum
  char*  zb       = take((size_t)NN*4 + (size_t)NN*4 + 256);
  int*   cursor   = (int*)zb;
  float* deg_w    = (float*)(cursor + NN);
  float* logsum   = (float*)(deg_w + NN);
  int zc = NN + NN + 64;

  float* rel6      = (float*)take(192*4);
  float* qc        = (float*)take(64*4);
  float* tdot      = (float*)take((size_t)NN*4);
  float* h_a       = (float*)take((size_t)NN*32*4);
  float* h_b       = (float*)take((size_t)NN*32*4);

  int nb  = (NN + 255) / 256;   // 196
  int nlb = (NN + 63) / 64;     // 782
  k_zero   <<<(zc+255)/256, 256, 0, stream>>>((float*)zb, zc);
  k_fillcsr<<<NPART*CPB, 256, 0, stream>>>(node_in, node_out, ew, cursor, csr);
  k_sumw   <<<nb, 256, 0, stream>>>(csr, cursor, deg_w, logsum);
  k_prep   <<<1, 256, 0, stream>>>(qw, rel_W, rel_b, W1, b1, rel6, qc);
  k_init_h <<<(NN*DD+255)/256, 256, 0, stream>>>(hidx, h_a);

  float* hc = h_a;
  float* hn = h_b;
  for (int l = 0; l < 6; ++l){
    if (l == 5){
      k_dot<<<nb, 256, 0, stream>>>(hc, rel6, tdot);
      k_layer<true><<<nlb, 512, 0, stream>>>(hc, rel6, cursor, csr, hidx, tdot,
                                             lin_W, lin_b, deg_w, logsum,
                                             hn, out_pred, l);
    } else {
      k_layer<false><<<nlb, 512, 0, stream>>>(hc, rel6, cursor, csr, hidx, tdot,
                                              lin_W, lin_b, deg_w, logsum,
                                              hn, out_pred, l);
    }
    float* t1 = hc; hc = hn; hn = t1;
  }
  k_mlp<<<nb, 256, 0, stream>>>(hc, qc, W1, W2, b2, out_score);
}

// Round 19
// 453.392 us; speedup vs baseline: 1.1152x; 1.0171x over previous
//
#include <hip/hip_runtime.h>
#include <math.h>

#define NN 50000
#define EE 800000
#define DD 32
#define BSTR 64    // bucket stride (max degree ~45 at Poisson(16); +8 pad fits)
#define NPART 8    // node-range partitions, mapped to XCDs via blockIdx&7
#define CPB 128    // edge chunks per partition (grid = 8*128 = 1024 blocks)

typedef float v2f __attribute__((ext_vector_type(2)));

// ---------------- setup kernels ----------------

__global__ __launch_bounds__(256) void k_zero(float* p, int count){
  int i = blockIdx.x*256 + threadIdx.x;
  if (i < count) p[i] = 0.f;
}

// XCD-partitioned one-pass CSR build (R16-proven: cut write-amp 51->~12 MB).
__global__ __launch_bounds__(256) void k_fillcsr(const int* __restrict__ node_in,
                                                 const int* __restrict__ node_out,
                                                 const float* __restrict__ ew,
                                                 int* __restrict__ cursor,
                                                 int2* __restrict__ csr){
  int part  = blockIdx.x & (NPART-1);
  int group = blockIdx.x >> 3;
  const int per = (EE + CPB - 1) / CPB;   // 6250
  int e0 = group * per;
  int e1 = (e0 + per < EE) ? (e0 + per) : EE;
  unsigned lo = (unsigned)part * 6250u;
  unsigned hi = lo + 6250u;
  for (int e = e0 + threadIdx.x; e < e1; e += 256){
    unsigned o = (unsigned)node_out[e];
    if (o >= lo && o < hi){
      int pos = atomicAdd(&cursor[o], 1);
      int2 v; v.x = node_in[e]; v.y = __float_as_int(ew[e]);
      csr[o*BSTR + pos] = v;
    }
  }
}

// per-node sum(w): 8-lane group per node, coalesced bucket reads, shfl_xor
// reduce; zero the 8-entry pad tail in parallel; block logsum reduce.
__global__ __launch_bounds__(256) void k_sumw(int2* __restrict__ csr,
                                              const int* __restrict__ cursor,
                                              float* __restrict__ deg_w,
                                              float* __restrict__ logsum){
  __shared__ float sf[256];
  int t = threadIdx.x;
  int g = t >> 3, lane = t & 7;
  int n = blockIdx.x*32 + g;
  float s = 0.f;
  if (n < NN){
    int deg = cursor[n];
    int2* row = csr + n*BSTR;
    for (int i = lane; i < deg; i += 8) s += __int_as_float(row[i].y);
    s += __shfl_xor(s, 1);
    s += __shfl_xor(s, 2);
    s += __shfl_xor(s, 4);
    row[deg + lane] = make_int2(0, 0);   // 8 pads, one per lane
    if (lane == 0) deg_w[n] = s;
  }
  sf[t] = (n < NN && lane == 0) ? logf(s + 1.f) : 0.f;
  __syncthreads();
  for (int off = 128; off > 0; off >>= 1){
    if (t < off) sf[t] += sf[t+off];
    __syncthreads();
  }
  if (t == 0) atomicAdd(logsum, sf[0]);
}

// rel_input per layer (6x32), query-part of final MLP (64), and layer-0
// W column-sums over the h-part rows (boundary input is constant per node).
__global__ __launch_bounds__(320) void k_prep(const float* __restrict__ qw,
                                              const float* __restrict__ rel_W,
                                              const float* __restrict__ rel_b,
                                              const float* __restrict__ W1,
                                              const float* __restrict__ b1,
                                              const float* __restrict__ lin_W,
                                              float* __restrict__ rel6,
                                              float* __restrict__ qc,
                                              float* __restrict__ wcol){
  int t = threadIdx.x;
  if (t < 192){
    int l = t >> 5, j = t & 31;
    float s = rel_b[t];
    for (int d = 0; d < 32; ++d) s += qw[d] * rel_W[l*1024 + d*32 + j];
    rel6[t] = s;
  } else if (t < 256){
    int j = t - 192;
    float s = b1[j];
    for (int k = 0; k < 32; ++k) s += qw[k] * W1[(32+k)*64 + j];
    qc[j] = s;
  } else if (t < 288){
    int j = t - 256;
    float s = 0.f;
    for (int k = 0; k < 32; ++k) s += lin_W[k*32 + j];   // layer 0, h-part rows
    wcol[j] = s;
  }
}

// t[n] = dot(h[n], rel_layer5) for msg_score
__global__ __launch_bounds__(256) void k_dot(const float* __restrict__ h,
                                             const float* __restrict__ rel6,
                                             float* __restrict__ tdot){
  int n0 = blockIdx.x*256 + threadIdx.x;
  int n = (n0 < NN) ? n0 : NN-1;
  const float* relr = rel6 + 5*32;
  float s = 0.f;
  #pragma unroll
  for (int d = 0; d < 32; ++d) s += h[n*32 + d] * relr[d];
  if (n0 < NN) tdot[n0] = s;
}

// ---------------- layer 0 (specialized: boundary input) ----------------
// Layer-0 input h[n][d] = (n==hidx ? 0 : 100) -- constant across dims. So
// phase 1 needs NO h gathers: per edge hv = (src==hidx?0:100) scalar, and
// the per-dim stats are scalar*rel_d. Phase 2's x-part collapses to
// bnd * colsum(W0) (precomputed wcol). ~4x faster than the generic layer.
__global__ __launch_bounds__(512, 6) void k_layer0(const float* __restrict__ rel6,
                                               const int* __restrict__ cursor,
                                               const int2* __restrict__ csr,
                                               const int* __restrict__ hidx,
                                               const float* __restrict__ lin_W,
                                               const float* __restrict__ lin_b,
                                               const float* __restrict__ wcol,
                                               const float* __restrict__ deg_w,
                                               const float* __restrict__ logsum,
                                               float* __restrict__ h_next){
  __shared__ float sh[128*65];
  int tid = threadIdx.x;
  int base = blockIdx.x * 64;
  int hv0 = *hidx;

  // ---- phase 1: scalar aggregation (csr scan only) ----
  {
    int nl   = tid >> 3;
    int quad = tid & 7;
    float4 r4 = ((const float4*)(rel6))[quad];   // layer 0
    int n0 = base + nl;
    int n = (n0 < NN) ? n0 : NN-1;
    int deg = cursor[n];
    int s0 = n*BSTR, s1 = s0 + deg;
    float S1=0.f, S2=0.f, M=-INFINITY, m=INFINITY;

#define ACCS(C) { \
    float w  = __int_as_float(C.y); \
    float hv = (C.x == hv0) ? 0.f : 100.f; \
    float wm = w * hv; \
    S1 += wm; S2 += wm * hv; \
    M = fmaxf(M, wm); m = fminf(m, wm); }

    int2 cA = csr[s0],   cB = csr[s0+1], cC = csr[s0+2], cD = csr[s0+3];
    int e = s0;
    for (; e + 4 <= s1; e += 4){
      int2 nA = csr[e+4], nB = csr[e+5], nC = csr[e+6], nD = csr[e+7];
      ACCS(cA) ACCS(cB) ACCS(cC) ACCS(cD)
      cA = nA; cB = nB; cC = nC; cD = nD;
    }
    if (e < s1){
      ACCS(cA)
      if (e + 1 < s1){
        ACCS(cB)
        if (e + 2 < s1) ACCS(cC)
      }
    }
#undef ACCS

    float bnd = (n == hv0) ? 0.f : 100.f;
    float cntf = (float)(deg + 1);
#define FIN(cc, rc) { \
    float mxv, mnv; \
    if (deg > 0){ \
      float em = (rc >= 0.f) ? rc*M : rc*m; \
      float en = (rc >= 0.f) ? rc*m : rc*M; \
      mxv = fmaxf(em, bnd); mnv = fminf(en, bnd); \
    } else { mxv = bnd; mnv = bnd; } \
    float meanv = (rc*S1 + bnd) / cntf; \
    float sq    = (rc*rc*S2 + bnd*bnd) / cntf; \
    float sdv   = sqrtf(fmaxf(sq - meanv*meanv, 1e-6f)); \
    int d = quad*4 + cc; \
    sh[(d*4+0)*65 + nl] = meanv; \
    sh[(d*4+1)*65 + nl] = mxv; \
    sh[(d*4+2)*65 + nl] = mnv; \
    sh[(d*4+3)*65 + nl] = sdv; }
    FIN(0, r4.x) FIN(1, r4.y) FIN(2, r4.z) FIN(3, r4.w)
#undef FIN
  }
  __syncthreads();

  // ---- phase 2: linear; x-part = bnd * wcol (boundary input) ----
  {
    const float* Wl = lin_W;   // layer 0
    int lane = tid & 63;
    int j0 = __builtin_amdgcn_readfirstlane((tid >> 6) * 4);
    int n0 = base + lane;
    int n = (n0 < NN) ? n0 : NN-1;
    float mean = *logsum / (float)NN;
    float sc = logf(deg_w[n] + 1.f) / mean;
    float iv = 1.f / fmaxf(sc, 0.01f);
    float bndn = (n == hv0) ? 0.f : 100.f;
    v2f a01, a23;
    a01[0] = lin_b[j0+0] + bndn*wcol[j0+0];
    a01[1] = lin_b[j0+1] + bndn*wcol[j0+1];
    a23[0] = lin_b[j0+2] + bndn*wcol[j0+2];
    a23[1] = lin_b[j0+3] + bndn*wcol[j0+3];

    for (int kp = 0; kp < 128; ++kp){
      float f = sh[kp*65 + lane];
      int d = kp >> 2, c = kp & 3;
      const v2f* w2 = (const v2f*)(Wl + (32 + d*12 + c*3)*32 + j0);
      float f1 = f*sc, f2 = f*iv;
      v2f fv;  fv[0]=f;  fv[1]=f;
      v2f f1v; f1v[0]=f1; f1v[1]=f1;
      v2f f2v; f2v[0]=f2; f2v[1]=f2;
      a01 += fv*w2[0] + f1v*w2[16] + f2v*w2[32];
      a23 += fv*w2[1] + f1v*w2[17] + f2v*w2[33];
    }

    if (n0 < NN){
      float vs[4] = { a01[0], a01[1], a23[0], a23[1] };
      #pragma unroll
      for (int j = 0; j < 4; ++j)
        h_next[n0*32 + j0 + j] = fmaxf(vs[j], 0.f);
    }
  }
}

// ---------------- fused per-layer kernel (layers 1..5) ----------------
// R18-proven structure: unroll-4 issue-then-wait phase 1, packed-fp32
// j-split phase 2 with inline scales. See R18 notes.
template<bool PRED>
__global__ __launch_bounds__(512, 6) void k_layer(const float* __restrict__ h,
                                               const float* __restrict__ rel6,
                                               const int* __restrict__ cursor,
                                               const int2* __restrict__ csr,
                                               const int* __restrict__ hidx,
                                               const float* __restrict__ tdot,
                                               const float* __restrict__ lin_W,
                                               const float* __restrict__ lin_b,
                                               const float* __restrict__ deg_w,
                                               const float* __restrict__ logsum,
                                               float* __restrict__ h_next,
                                               float* __restrict__ pred_out,
                                               int l){
  __shared__ float sh[128*65];
  int tid = threadIdx.x;
  int base = blockIdx.x * 64;
  int hv0 = *hidx;

  // ---- phase 1: aggregation (one 8-lane group per node, unroll-4) ----
  {
    int nl   = tid >> 3;
    int quad = tid & 7;
    float4 r4 = ((const float4*)(rel6 + l*32))[quad];
    int n0 = base + nl;
    bool valid = n0 < NN;
    int n = valid ? n0 : NN-1;
    int deg = cursor[n];
    int s0 = n*BSTR, s1 = s0 + deg;
    float S10=0.f,S11=0.f,S12=0.f,S13=0.f;
    float S20=0.f,S21=0.f,S22=0.f,S23=0.f;
    float M0=-INFINITY,M1=-INFINITY,M2=-INFINITY,M3=-INFINITY;
    float m0=INFINITY,m1=INFINITY,m2=INFINITY,m3=INFINITY;
    float best=-INFINITY; int bi=NN;

#define ACC1(C, A, T) { \
    float w = __int_as_float(C.y); \
    float p0=w*A.x, p1=w*A.y, p2=w*A.z, p3=w*A.w; \
    S10+=p0; S11+=p1; S12+=p2; S13+=p3; \
    S20+=p0*A.x; S21+=p1*A.y; S22+=p2*A.z; S23+=p3*A.w; \
    M0=fmaxf(M0,p0); M1=fmaxf(M1,p1); M2=fmaxf(M2,p2); M3=fmaxf(M3,p3); \
    m0=fminf(m0,p0); m1=fminf(m1,p1); m2=fminf(m2,p2); m3=fminf(m3,p3); \
    if (PRED){ \
      float sv = w*T; \
      if (sv > best){ best = sv; bi = C.x; } \
      else if (sv == best && C.x < bi) bi = C.x; \
    } }

    int2 cA = csr[s0],   cB = csr[s0+1], cC = csr[s0+2], cD = csr[s0+3];
    int e = s0;
    for (; e + 4 <= s1; e += 4){
      float4 a  = ((const float4*)(h + cA.x*32))[quad];
      float4 b  = ((const float4*)(h + cB.x*32))[quad];
      float4 c4 = ((const float4*)(h + cC.x*32))[quad];
      float4 d4 = ((const float4*)(h + cD.x*32))[quad];
      float tA=0.f, tB=0.f, tC=0.f, tD=0.f;
      if (PRED){ tA = tdot[cA.x]; tB = tdot[cB.x]; tC = tdot[cC.x]; tD = tdot[cD.x]; }
      int2 nA = csr[e+4], nB = csr[e+5], nC = csr[e+6], nD = csr[e+7];
      ACC1(cA, a, tA)
      ACC1(cB, b, tB)
      ACC1(cC, c4, tC)
      ACC1(cD, d4, tD)
      cA = nA; cB = nB; cC = nC; cD = nD;
    }
    if (e < s1){
      float4 a = ((const float4*)(h + cA.x*32))[quad];
      float tA = 0.f; if (PRED) tA = tdot[cA.x];
      ACC1(cA, a, tA)
      if (e + 1 < s1){
        float4 b = ((const float4*)(h + cB.x*32))[quad];
        float tB = 0.f; if (PRED) tB = tdot[cB.x];
        ACC1(cB, b, tB)
        if (e + 2 < s1){
          float4 c4 = ((const float4*)(h + cC.x*32))[quad];
          float tC = 0.f; if (PRED) tC = tdot[cC.x];
          ACC1(cC, c4, tC)
        }
      }
    }
#undef ACC1

    float bnd = (n == hv0) ? 0.f : 100.f;
    float cntf = (float)(deg + 1);
#define FIN(cc, rc, S1c, S2c, Mc, mc) { \
    float mxv, mnv; \
    if (deg > 0){ \
      float em = (rc >= 0.f) ? rc*Mc : rc*mc; \
      float en = (rc >= 0.f) ? rc*mc : rc*Mc; \
      mxv = fmaxf(em, bnd); mnv = fminf(en, bnd); \
    } else { mxv = bnd; mnv = bnd; } \
    float meanv = (rc*S1c + bnd) / cntf; \
    float sq    = (rc*rc*S2c + bnd*bnd) / cntf; \
    float sdv   = sqrtf(fmaxf(sq - meanv*meanv, 1e-6f)); \
    int d = quad*4 + cc; \
    sh[(d*4+0)*65 + nl] = meanv; \
    sh[(d*4+1)*65 + nl] = mxv; \
    sh[(d*4+2)*65 + nl] = mnv; \
    sh[(d*4+3)*65 + nl] = sdv; }
    FIN(0, r4.x, S10, S20, M0, m0)
    FIN(1, r4.y, S11, S21, M1, m1)
    FIN(2, r4.z, S12, S22, M2, m2)
    FIN(3, r4.w, S13, S23, M3, m3)
#undef FIN
    if (PRED && valid && quad == 0){
      float ss = (n == hv0) ? 0.f : 3200.f;   // boundary self-loop row sum, w=1
      if (ss > best){ best = ss; bi = n; }
      else if (ss == best && n < bi) bi = n;
      pred_out[n] = (float)bi;
    }
  }
  __syncthreads();

  // ---- phase 2: linear (8 waves, wave w -> j0 = w*4; node = lane) ----
  {
    const float* Wl = lin_W + (size_t)l * 13312;
    int lane = tid & 63;
    int j0 = __builtin_amdgcn_readfirstlane((tid >> 6) * 4);
    int n0 = base + lane;
    int n = (n0 < NN) ? n0 : NN-1;
    float mean = *logsum / (float)NN;
    float sc = logf(deg_w[n] + 1.f) / mean;
    float iv = 1.f / fmaxf(sc, 0.01f);
    const float4* hr = (const float4*)(h + (size_t)n*32);
    float4 x0=hr[0],x1=hr[1],x2=hr[2],x3=hr[3],x4=hr[4],x5=hr[5],x6=hr[6],x7=hr[7];
    v2f a01, a23;
    a01[0] = lin_b[l*32 + j0 + 0]; a01[1] = lin_b[l*32 + j0 + 1];
    a23[0] = lin_b[l*32 + j0 + 2]; a23[1] = lin_b[l*32 + j0 + 3];

#define KONE(XV, K) { \
    v2f xv2; xv2[0] = XV; xv2[1] = XV; \
    const v2f* wr2 = (const v2f*)(Wl + (K)*32 + j0); \
    a01 += xv2 * wr2[0]; \
    a23 += xv2 * wr2[1]; }
#define KQ(X, KB) KONE(X.x, KB+0) KONE(X.y, KB+1) KONE(X.z, KB+2) KONE(X.w, KB+3)
    KQ(x0, 0) KQ(x1, 4) KQ(x2, 8) KQ(x3, 12)
    KQ(x4, 16) KQ(x5, 20) KQ(x6, 24) KQ(x7, 28)
#undef KQ
#undef KONE

    for (int kp = 0; kp < 128; ++kp){
      float f = sh[kp*65 + lane];
      int d = kp >> 2, c = kp & 3;
      const v2f* w2 = (const v2f*)(Wl + (32 + d*12 + c*3)*32 + j0);
      float f1 = f*sc, f2 = f*iv;
      v2f fv;  fv[0]=f;  fv[1]=f;
      v2f f1v; f1v[0]=f1; f1v[1]=f1;
      v2f f2v; f2v[0]=f2; f2v[1]=f2;
      a01 += fv*w2[0] + f1v*w2[16] + f2v*w2[32];
      a23 += fv*w2[1] + f1v*w2[17] + f2v*w2[33];
    }

    if (n0 < NN){
      float vs[4] = { a01[0], a01[1], a23[0], a23[1] };
      #pragma unroll
      for (int j = 0; j < 4; ++j)
        h_next[n0*32 + j0 + j] = fmaxf(vs[j], 0.f);
    }
  }
}

// ---------------- final MLP (reads h row-major) ----------------
__global__ __launch_bounds__(256) void k_mlp(const float* __restrict__ h,
                                             const float* __restrict__ qc,
                                             const float* __restrict__ W1,
                                             const float* __restrict__ W2,
                                             const float* __restrict__ b2,
                                             float* __restrict__ out_score){
  int n0 = blockIdx.x*256 + threadIdx.x;
  int n = (n0 < NN) ? n0 : NN-1;
  float xr[32];
  const float4* hr = (const float4*)(h + (size_t)n*32);
  #pragma unroll
  for (int q = 0; q < 8; ++q){
    float4 x = hr[q];
    xr[q*4+0]=x.x; xr[q*4+1]=x.y; xr[q*4+2]=x.z; xr[q*4+3]=x.w;
  }
  float acc[64];
  #pragma unroll
  for (int j = 0; j < 64; ++j) acc[j] = qc[j];
  #pragma unroll
  for (int k = 0; k < 32; ++k){
    float xv = xr[k];
    const float* wr = W1 + k*64;
    #pragma unroll
    for (int j = 0; j < 64; ++j) acc[j] += xv * wr[j];
  }
  float s = b2[0];
  #pragma unroll
  for (int j = 0; j < 64; ++j) s += fmaxf(acc[j], 0.f) * W2[j];
  if (n0 < NN) out_score[n0] = s;
}

// ---------------- host launch ----------------
extern "C" void kernel_launch(void* const* d_in, const int* in_sizes, int n_in,
                              void* d_out, int out_size, void* d_ws, size_t ws_size,
                              hipStream_t stream){
  const int*   node_in  = (const int*)d_in[0];
  const int*   node_out = (const int*)d_in[1];
  const float* ew       = (const float*)d_in[2];
  const int*   hidx     = (const int*)d_in[3];
  const float* qw       = (const float*)d_in[4];
  const float* rel_W    = (const float*)d_in[5];
  const float* rel_b    = (const float*)d_in[6];
  const float* lin_W    = (const float*)d_in[7];
  const float* lin_b    = (const float*)d_in[8];
  const float* W1       = (const float*)d_in[9];
  const float* b1       = (const float*)d_in[10];
  const float* W2       = (const float*)d_in[11];
  const float* b2       = (const float*)d_in[12];
  float* out_score = (float*)d_out;
  float* out_pred  = out_score + NN;

  char* w = (char*)d_ws;
  size_t off = 0;
  auto take = [&](size_t bytes)->char*{
    char* p = w + off;
    off = (off + bytes + 255) & ~(size_t)255;
    return p;
  };
  size_t bucket_elems = (size_t)NN * BSTR;            // int2 entries
  int2*  csr      = (int2*)take(bucket_elems*8);
  // contiguous zero block: cursor | deg_w | logsum
  char*  zb       = take((size_t)NN*4 + (size_t)NN*4 + 256);
  int*   cursor   = (int*)zb;
  float* deg_w    = (float*)(cursor + NN);
  float* logsum   = (float*)(deg_w + NN);
  int zc = NN + NN + 64;

  float* rel6      = (float*)take(192*4);
  float* qc        = (float*)take(64*4);
  float* wcol      = (float*)take(32*4);
  float* tdot      = (float*)take((size_t)NN*4);
  float* h_a       = (float*)take((size_t)NN*32*4);
  float* h_b       = (float*)take((size_t)NN*32*4);

  int nb  = (NN + 255) / 256;   // 196
  int nsb = (NN + 31) / 32;     // 1563 (k_sumw: 32 nodes/block)
  int nlb = (NN + 63) / 64;     // 782
  k_zero   <<<(zc+255)/256, 256, 0, stream>>>((float*)zb, zc);
  k_fillcsr<<<NPART*CPB, 256, 0, stream>>>(node_in, node_out, ew, cursor, csr);
  k_sumw   <<<nsb, 256, 0, stream>>>(csr, cursor, deg_w, logsum);
  k_prep   <<<1, 320, 0, stream>>>(qw, rel_W, rel_b, W1, b1, lin_W, rel6, qc, wcol);

  // layer 0 (specialized, no h input)
  k_layer0<<<nlb, 512, 0, stream>>>(rel6, cursor, csr, hidx, lin_W, lin_b,
                                    wcol, deg_w, logsum, h_a);

  float* hc = h_a;
  float* hn = h_b;
  for (int l = 1; l < 6; ++l){
    if (l == 5){
      k_dot<<<nb, 256, 0, stream>>>(hc, rel6, tdot);
      k_layer<true><<<nlb, 512, 0, stream>>>(hc, rel6, cursor, csr, hidx, tdot,
                                             lin_W, lin_b, deg_w, logsum,
                                             hn, out_pred, l);
    } else {
      k_layer<false><<<nlb, 512, 0, stream>>>(hc, rel6, cursor, csr, hidx, tdot,
                                              lin_W, lin_b, deg_w, logsum,
                                              hn, out_pred, l);
    }
    float* t1 = hc; hc = hn; hn = t1;
  }
  k_mlp<<<nb, 256, 0, stream>>>(hc, qc, W1, W2, b2, out_score);
}

// Round 20
// 441.309 us; speedup vs baseline: 1.1458x; 1.0274x over previous
//
#include <hip/hip_runtime.h>
#include <math.h>

#define NN 50000
#define EE 800000
#define DD 32
#define BSTR 64    // bucket stride (max degree ~45 at Poisson(16); +8 pad fits)
#define NPART 8    // node-range partitions, mapped to XCDs via blockIdx&7
#define CPB 128    // edge chunks per partition (grid = 8*128 = 1024 blocks)

typedef float v2f __attribute__((ext_vector_type(2)));

// ---------------- setup kernels ----------------

__global__ __launch_bounds__(256) void k_zero(float* p, int count){
  int i = blockIdx.x*256 + threadIdx.x;
  if (i < count) p[i] = 0.f;
}

// XCD-partitioned one-pass CSR build (R16-proven: cut write-amp 51->~12 MB).
__global__ __launch_bounds__(256) void k_fillcsr(const int* __restrict__ node_in,
                                                 const int* __restrict__ node_out,
                                                 const float* __restrict__ ew,
                                                 int* __restrict__ cursor,
                                                 int2* __restrict__ csr){
  int part  = blockIdx.x & (NPART-1);
  int group = blockIdx.x >> 3;
  const int per = (EE + CPB - 1) / CPB;   // 6250
  int e0 = group * per;
  int e1 = (e0 + per < EE) ? (e0 + per) : EE;
  unsigned lo = (unsigned)part * 6250u;
  unsigned hi = lo + 6250u;
  for (int e = e0 + threadIdx.x; e < e1; e += 256){
    unsigned o = (unsigned)node_out[e];
    if (o >= lo && o < hi){
      int pos = atomicAdd(&cursor[o], 1);
      int2 v; v.x = node_in[e]; v.y = __float_as_int(ew[e]);
      csr[o*BSTR + pos] = v;
    }
  }
}

// per-node sum(w): 8-lane group per node, coalesced bucket reads, shfl_xor
// reduce; zero the 8-entry pad tail in parallel; block logsum reduce.
__global__ __launch_bounds__(256) void k_sumw(int2* __restrict__ csr,
                                              const int* __restrict__ cursor,
                                              float* __restrict__ deg_w,
                                              float* __restrict__ logsum){
  __shared__ float sf[256];
  int t = threadIdx.x;
  int g = t >> 3, lane = t & 7;
  int n = blockIdx.x*32 + g;
  float s = 0.f;
  if (n < NN){
    int deg = cursor[n];
    int2* row = csr + n*BSTR;
    for (int i = lane; i < deg; i += 8) s += __int_as_float(row[i].y);
    s += __shfl_xor(s, 1);
    s += __shfl_xor(s, 2);
    s += __shfl_xor(s, 4);
    row[deg + lane] = make_int2(0, 0);   // 8 pads, one per lane
    if (lane == 0) deg_w[n] = s;
  }
  sf[t] = (n < NN && lane == 0) ? logf(s + 1.f) : 0.f;
  __syncthreads();
  for (int off = 128; off > 0; off >>= 1){
    if (t < off) sf[t] += sf[t+off];
    __syncthreads();
  }
  if (t == 0) atomicAdd(logsum, sf[0]);
}

// rel_input per layer (6x32), query-part of final MLP (64), and layer-0
// W column-sums over the h-part rows (boundary input is constant per node).
__global__ __launch_bounds__(320) void k_prep(const float* __restrict__ qw,
                                              const float* __restrict__ rel_W,
                                              const float* __restrict__ rel_b,
                                              const float* __restrict__ W1,
                                              const float* __restrict__ b1,
                                              const float* __restrict__ lin_W,
                                              float* __restrict__ rel6,
                                              float* __restrict__ qc,
                                              float* __restrict__ wcol){
  int t = threadIdx.x;
  if (t < 192){
    int l = t >> 5, j = t & 31;
    float s = rel_b[t];
    for (int d = 0; d < 32; ++d) s += qw[d] * rel_W[l*1024 + d*32 + j];
    rel6[t] = s;
  } else if (t < 256){
    int j = t - 192;
    float s = b1[j];
    for (int k = 0; k < 32; ++k) s += qw[k] * W1[(32+k)*64 + j];
    qc[j] = s;
  } else if (t < 288){
    int j = t - 256;
    float s = 0.f;
    for (int k = 0; k < 32; ++k) s += lin_W[k*32 + j];   // layer 0, h-part rows
    wcol[j] = s;
  }
}

// t[n] = dot(h[n], rel_layer5) for msg_score
__global__ __launch_bounds__(256) void k_dot(const float* __restrict__ h,
                                             const float* __restrict__ rel6,
                                             float* __restrict__ tdot){
  int n0 = blockIdx.x*256 + threadIdx.x;
  int n = (n0 < NN) ? n0 : NN-1;
  const float* relr = rel6 + 5*32;
  float s = 0.f;
  #pragma unroll
  for (int d = 0; d < 32; ++d) s += h[n*32 + d] * relr[d];
  if (n0 < NN) tdot[n0] = s;
}

// ---------------- layer 0 (specialized: boundary input) ----------------
__global__ __launch_bounds__(512, 6) void k_layer0(const float* __restrict__ rel6,
                                               const int* __restrict__ cursor,
                                               const int2* __restrict__ csr,
                                               const int* __restrict__ hidx,
                                               const float* __restrict__ lin_W,
                                               const float* __restrict__ lin_b,
                                               const float* __restrict__ wcol,
                                               const float* __restrict__ deg_w,
                                               const float* __restrict__ logsum,
                                               float* __restrict__ h_next){
  __shared__ float sh[128*65];
  int tid = threadIdx.x;
  int base = blockIdx.x * 64;
  int hv0 = *hidx;

  // ---- phase 1: scalar aggregation (csr scan only) ----
  {
    int nl   = tid >> 3;
    int quad = tid & 7;
    float4 r4 = ((const float4*)(rel6))[quad];   // layer 0
    int n0 = base + nl;
    int n = (n0 < NN) ? n0 : NN-1;
    int deg = cursor[n];
    int s0 = n*BSTR, s1 = s0 + deg;
    float S1=0.f, S2=0.f, M=-INFINITY, m=INFINITY;

#define ACCS(C) { \
    float w  = __int_as_float(C.y); \
    float hv = (C.x == hv0) ? 0.f : 100.f; \
    float wm = w * hv; \
    S1 += wm; S2 += wm * hv; \
    M = fmaxf(M, wm); m = fminf(m, wm); }

    int2 cA = csr[s0],   cB = csr[s0+1], cC = csr[s0+2], cD = csr[s0+3];
    int e = s0;
    for (; e + 4 <= s1; e += 4){
      int2 nA = csr[e+4], nB = csr[e+5], nC = csr[e+6], nD = csr[e+7];
      ACCS(cA) ACCS(cB) ACCS(cC) ACCS(cD)
      cA = nA; cB = nB; cC = nC; cD = nD;
    }
    if (e < s1){
      ACCS(cA)
      if (e + 1 < s1){
        ACCS(cB)
        if (e + 2 < s1) ACCS(cC)
      }
    }
#undef ACCS

    float bnd = (n == hv0) ? 0.f : 100.f;
    float cntf = (float)(deg + 1);
#define FIN(cc, rc) { \
    float mxv, mnv; \
    if (deg > 0){ \
      float em = (rc >= 0.f) ? rc*M : rc*m; \
      float en = (rc >= 0.f) ? rc*m : rc*M; \
      mxv = fmaxf(em, bnd); mnv = fminf(en, bnd); \
    } else { mxv = bnd; mnv = bnd; } \
    float meanv = (rc*S1 + bnd) / cntf; \
    float sq    = (rc*rc*S2 + bnd*bnd) / cntf; \
    float sdv   = sqrtf(fmaxf(sq - meanv*meanv, 1e-6f)); \
    int d = quad*4 + cc; \
    sh[(d*4+0)*65 + nl] = meanv; \
    sh[(d*4+1)*65 + nl] = mxv; \
    sh[(d*4+2)*65 + nl] = mnv; \
    sh[(d*4+3)*65 + nl] = sdv; }
    FIN(0, r4.x) FIN(1, r4.y) FIN(2, r4.z) FIN(3, r4.w)
#undef FIN
  }
  __syncthreads();

  // ---- phase 2: linear; x-part = bnd * wcol (boundary input) ----
  {
    const float* Wl = lin_W;   // layer 0
    int lane = tid & 63;
    int j0 = __builtin_amdgcn_readfirstlane((tid >> 6) * 4);
    int n0 = base + lane;
    int n = (n0 < NN) ? n0 : NN-1;
    float mean = *logsum / (float)NN;
    float sc = logf(deg_w[n] + 1.f) / mean;
    float iv = 1.f / fmaxf(sc, 0.01f);
    float bndn = (n == hv0) ? 0.f : 100.f;
    v2f a01, a23;
    a01[0] = lin_b[j0+0] + bndn*wcol[j0+0];
    a01[1] = lin_b[j0+1] + bndn*wcol[j0+1];
    a23[0] = lin_b[j0+2] + bndn*wcol[j0+2];
    a23[1] = lin_b[j0+3] + bndn*wcol[j0+3];

    for (int kp = 0; kp < 128; ++kp){
      float f = sh[kp*65 + lane];
      int d = kp >> 2, c = kp & 3;
      const v2f* w2 = (const v2f*)(Wl + (32 + d*12 + c*3)*32 + j0);
      float f1 = f*sc, f2 = f*iv;
      v2f fv;  fv[0]=f;  fv[1]=f;
      v2f f1v; f1v[0]=f1; f1v[1]=f1;
      v2f f2v; f2v[0]=f2; f2v[1]=f2;
      a01 += fv*w2[0] + f1v*w2[16] + f2v*w2[32];
      a23 += fv*w2[1] + f1v*w2[17] + f2v*w2[33];
    }

    if (n0 < NN){
      float vs[4] = { a01[0], a01[1], a23[0], a23[1] };
      #pragma unroll
      for (int j = 0; j < 4; ++j)
        h_next[n0*32 + j0 + j] = fmaxf(vs[j], 0.f);
    }
  }
}

// ---------------- fused per-layer kernel (layers 1..5) ----------------
// R18-proven structure: unroll-4 issue-then-wait phase 1, packed-fp32
// j-split phase 2 with inline scales. PRED (l=5): predecessor tracking in
// phase 1, and the final MLP fused into the epilogue (h6 staged in sh,
// wave-uniform W1 s_loads, LDS partial-reduce) -- h_next store and the
// separate k_mlp kernel are eliminated for the last layer.
template<bool PRED>
__global__ __launch_bounds__(512, 6) void k_layer(const float* __restrict__ h,
                                               const float* __restrict__ rel6,
                                               const int* __restrict__ cursor,
                                               const int2* __restrict__ csr,
                                               const int* __restrict__ hidx,
                                               const float* __restrict__ tdot,
                                               const float* __restrict__ lin_W,
                                               const float* __restrict__ lin_b,
                                               const float* __restrict__ deg_w,
                                               const float* __restrict__ logsum,
                                               float* __restrict__ h_next,
                                               float* __restrict__ pred_out,
                                               const float* __restrict__ qc,
                                               const float* __restrict__ W1,
                                               const float* __restrict__ W2,
                                               const float* __restrict__ b2,
                                               float* __restrict__ out_score,
                                               int l){
  __shared__ float sh[128*65];
  int tid = threadIdx.x;
  int base = blockIdx.x * 64;
  int hv0 = *hidx;

  // ---- phase 1: aggregation (one 8-lane group per node, unroll-4) ----
  {
    int nl   = tid >> 3;
    int quad = tid & 7;
    float4 r4 = ((const float4*)(rel6 + l*32))[quad];
    int n0 = base + nl;
    bool valid = n0 < NN;
    int n = valid ? n0 : NN-1;
    int deg = cursor[n];
    int s0 = n*BSTR, s1 = s0 + deg;
    float S10=0.f,S11=0.f,S12=0.f,S13=0.f;
    float S20=0.f,S21=0.f,S22=0.f,S23=0.f;
    float M0=-INFINITY,M1=-INFINITY,M2=-INFINITY,M3=-INFINITY;
    float m0=INFINITY,m1=INFINITY,m2=INFINITY,m3=INFINITY;
    float best=-INFINITY; int bi=NN;

#define ACC1(C, A, T) { \
    float w = __int_as_float(C.y); \
    float p0=w*A.x, p1=w*A.y, p2=w*A.z, p3=w*A.w; \
    S10+=p0; S11+=p1; S12+=p2; S13+=p3; \
    S20+=p0*A.x; S21+=p1*A.y; S22+=p2*A.z; S23+=p3*A.w; \
    M0=fmaxf(M0,p0); M1=fmaxf(M1,p1); M2=fmaxf(M2,p2); M3=fmaxf(M3,p3); \
    m0=fminf(m0,p0); m1=fminf(m1,p1); m2=fminf(m2,p2); m3=fminf(m3,p3); \
    if (PRED){ \
      float sv = w*T; \
      if (sv > best){ best = sv; bi = C.x; } \
      else if (sv == best && C.x < bi) bi = C.x; \
    } }

    int2 cA = csr[s0],   cB = csr[s0+1], cC = csr[s0+2], cD = csr[s0+3];
    int e = s0;
    for (; e + 4 <= s1; e += 4){
      float4 a  = ((const float4*)(h + cA.x*32))[quad];
      float4 b  = ((const float4*)(h + cB.x*32))[quad];
      float4 c4 = ((const float4*)(h + cC.x*32))[quad];
      float4 d4 = ((const float4*)(h + cD.x*32))[quad];
      float tA=0.f, tB=0.f, tC=0.f, tD=0.f;
      if (PRED){ tA = tdot[cA.x]; tB = tdot[cB.x]; tC = tdot[cC.x]; tD = tdot[cD.x]; }
      int2 nA = csr[e+4], nB = csr[e+5], nC = csr[e+6], nD = csr[e+7];
      ACC1(cA, a, tA)
      ACC1(cB, b, tB)
      ACC1(cC, c4, tC)
      ACC1(cD, d4, tD)
      cA = nA; cB = nB; cC = nC; cD = nD;
    }
    if (e < s1){
      float4 a = ((const float4*)(h + cA.x*32))[quad];
      float tA = 0.f; if (PRED) tA = tdot[cA.x];
      ACC1(cA, a, tA)
      if (e + 1 < s1){
        float4 b = ((const float4*)(h + cB.x*32))[quad];
        float tB = 0.f; if (PRED) tB = tdot[cB.x];
        ACC1(cB, b, tB)
        if (e + 2 < s1){
          float4 c4 = ((const float4*)(h + cC.x*32))[quad];
          float tC = 0.f; if (PRED) tC = tdot[cC.x];
          ACC1(cC, c4, tC)
        }
      }
    }
#undef ACC1

    float bnd = (n == hv0) ? 0.f : 100.f;
    float cntf = (float)(deg + 1);
#define FIN(cc, rc, S1c, S2c, Mc, mc) { \
    float mxv, mnv; \
    if (deg > 0){ \
      float em = (rc >= 0.f) ? rc*Mc : rc*mc; \
      float en = (rc >= 0.f) ? rc*mc : rc*Mc; \
      mxv = fmaxf(em, bnd); mnv = fminf(en, bnd); \
    } else { mxv = bnd; mnv = bnd; } \
    float meanv = (rc*S1c + bnd) / cntf; \
    float sq    = (rc*rc*S2c + bnd*bnd) / cntf; \
    float sdv   = sqrtf(fmaxf(sq - meanv*meanv, 1e-6f)); \
    int d = quad*4 + cc; \
    sh[(d*4+0)*65 + nl] = meanv; \
    sh[(d*4+1)*65 + nl] = mxv; \
    sh[(d*4+2)*65 + nl] = mnv; \
    sh[(d*4+3)*65 + nl] = sdv; }
    FIN(0, r4.x, S10, S20, M0, m0)
    FIN(1, r4.y, S11, S21, M1, m1)
    FIN(2, r4.z, S12, S22, M2, m2)
    FIN(3, r4.w, S13, S23, M3, m3)
#undef FIN
    if (PRED && valid && quad == 0){
      float ss = (n == hv0) ? 0.f : 3200.f;   // boundary self-loop row sum, w=1
      if (ss > best){ best = ss; bi = n; }
      else if (ss == best && n < bi) bi = n;
      pred_out[n] = (float)bi;
    }
  }
  __syncthreads();

  // ---- phase 2: linear (8 waves, wave w -> j0 = w*4; node = lane) ----
  {
    const float* Wl = lin_W + (size_t)l * 13312;
    int lane = tid & 63;
    int j0 = __builtin_amdgcn_readfirstlane((tid >> 6) * 4);
    int n0 = base + lane;
    int n = (n0 < NN) ? n0 : NN-1;
    float mean = *logsum / (float)NN;
    float sc = logf(deg_w[n] + 1.f) / mean;
    float iv = 1.f / fmaxf(sc, 0.01f);
    const float4* hr = (const float4*)(h + (size_t)n*32);
    float4 x0=hr[0],x1=hr[1],x2=hr[2],x3=hr[3],x4=hr[4],x5=hr[5],x6=hr[6],x7=hr[7];
    v2f a01, a23;
    a01[0] = lin_b[l*32 + j0 + 0]; a01[1] = lin_b[l*32 + j0 + 1];
    a23[0] = lin_b[l*32 + j0 + 2]; a23[1] = lin_b[l*32 + j0 + 3];

#define KONE(XV, K) { \
    v2f xv2; xv2[0] = XV; xv2[1] = XV; \
    const v2f* wr2 = (const v2f*)(Wl + (K)*32 + j0); \
    a01 += xv2 * wr2[0]; \
    a23 += xv2 * wr2[1]; }
#define KQ(X, KB) KONE(X.x, KB+0) KONE(X.y, KB+1) KONE(X.z, KB+2) KONE(X.w, KB+3)
    KQ(x0, 0) KQ(x1, 4) KQ(x2, 8) KQ(x3, 12)
    KQ(x4, 16) KQ(x5, 20) KQ(x6, 24) KQ(x7, 28)
#undef KQ
#undef KONE

    for (int kp = 0; kp < 128; ++kp){
      float f = sh[kp*65 + lane];
      int d = kp >> 2, c = kp & 3;
      const v2f* w2 = (const v2f*)(Wl + (32 + d*12 + c*3)*32 + j0);
      float f1 = f*sc, f2 = f*iv;
      v2f fv;  fv[0]=f;  fv[1]=f;
      v2f f1v; f1v[0]=f1; f1v[1]=f1;
      v2f f2v; f2v[0]=f2; f2v[1]=f2;
      a01 += fv*w2[0] + f1v*w2[16] + f2v*w2[32];
      a23 += fv*w2[1] + f1v*w2[17] + f2v*w2[33];
    }

    float v0r = fmaxf(a01[0], 0.f), v1r = fmaxf(a01[1], 0.f);
    float v2r = fmaxf(a23[0], 0.f), v3r = fmaxf(a23[1], 0.f);

    if (!PRED){
      if (n0 < NN){
        h_next[n0*32 + j0 + 0] = v0r;
        h_next[n0*32 + j0 + 1] = v1r;
        h_next[n0*32 + j0 + 2] = v2r;
        h_next[n0*32 + j0 + 3] = v3r;
      }
    } else {
      // ---- fused final MLP (l=5): h6 never leaves the block ----
      __syncthreads();                    // all phase-2 sh reads complete
      sh[(j0+0)*65 + lane] = v0r;         // stage h6 rows 0..31
      sh[(j0+1)*65 + lane] = v1r;
      sh[(j0+2)*65 + lane] = v2r;
      sh[(j0+3)*65 + lane] = v3r;
      __syncthreads();
      int node = tid & 63;
      int grp  = __builtin_amdgcn_readfirstlane(tid >> 6);   // 0..7
      int jm = grp*8;                     // wave-uniform -> W1 s_loads
      v2f b0, b1v, b2v, b3;
      b0[0]=qc[jm+0]; b0[1]=qc[jm+1]; b1v[0]=qc[jm+2]; b1v[1]=qc[jm+3];
      b2v[0]=qc[jm+4]; b2v[1]=qc[jm+5]; b3[0]=qc[jm+6]; b3[1]=qc[jm+7];
      for (int k = 0; k < 32; ++k){
        float xv = sh[k*65 + node];
        const v2f* wr = (const v2f*)(W1 + k*64 + jm);
        v2f xv2; xv2[0]=xv; xv2[1]=xv;
        b0 += xv2*wr[0]; b1v += xv2*wr[1]; b2v += xv2*wr[2]; b3 += xv2*wr[3];
      }
      float part = fmaxf(b0[0],0.f)*W2[jm+0] + fmaxf(b0[1],0.f)*W2[jm+1]
                 + fmaxf(b1v[0],0.f)*W2[jm+2] + fmaxf(b1v[1],0.f)*W2[jm+3]
                 + fmaxf(b2v[0],0.f)*W2[jm+4] + fmaxf(b2v[1],0.f)*W2[jm+5]
                 + fmaxf(b3[0],0.f)*W2[jm+6] + fmaxf(b3[1],0.f)*W2[jm+7];
      sh[2080 + node*9 + grp] = part;     // past the 32 staged rows (2080)
      __syncthreads();
      if (tid < 64){
        float s = b2[0];
        #pragma unroll
        for (int g = 0; g < 8; ++g) s += sh[2080 + tid*9 + g];
        if (base + tid < NN) out_score[base + tid] = s;
      }
    }
  }
}

// ---------------- host launch ----------------
extern "C" void kernel_launch(void* const* d_in, const int* in_sizes, int n_in,
                              void* d_out, int out_size, void* d_ws, size_t ws_size,
                              hipStream_t stream){
  const int*   node_in  = (const int*)d_in[0];
  const int*   node_out = (const int*)d_in[1];
  const float* ew       = (const float*)d_in[2];
  const int*   hidx     = (const int*)d_in[3];
  const float* qw       = (const float*)d_in[4];
  const float* rel_W    = (const float*)d_in[5];
  const float* rel_b    = (const float*)d_in[6];
  const float* lin_W    = (const float*)d_in[7];
  const float* lin_b    = (const float*)d_in[8];
  const float* W1       = (const float*)d_in[9];
  const float* b1       = (const float*)d_in[10];
  const float* W2       = (const float*)d_in[11];
  const float* b2       = (const float*)d_in[12];
  float* out_score = (float*)d_out;
  float* out_pred  = out_score + NN;

  char* w = (char*)d_ws;
  size_t off = 0;
  auto take = [&](size_t bytes)->char*{
    char* p = w + off;
    off = (off + bytes + 255) & ~(size_t)255;
    return p;
  };
  size_t bucket_elems = (size_t)NN * BSTR;            // int2 entries
  int2*  csr      = (int2*)take(bucket_elems*8);
  // contiguous zero block: cursor | deg_w | logsum
  char*  zb       = take((size_t)NN*4 + (size_t)NN*4 + 256);
  int*   cursor   = (int*)zb;
  float* deg_w    = (float*)(cursor + NN);
  float* logsum   = (float*)(deg_w + NN);
  int zc = NN + NN + 64;

  float* rel6      = (float*)take(192*4);
  float* qc        = (float*)take(64*4);
  float* wcol      = (float*)take(32*4);
  float* tdot      = (float*)take((size_t)NN*4);
  float* h_a       = (float*)take((size_t)NN*32*4);
  float* h_b       = (float*)take((size_t)NN*32*4);

  int nb  = (NN + 255) / 256;   // 196
  int nsb = (NN + 31) / 32;     // 1563 (k_sumw: 32 nodes/block)
  int nlb = (NN + 63) / 64;     // 782
  k_zero   <<<(zc+255)/256, 256, 0, stream>>>((float*)zb, zc);
  k_fillcsr<<<NPART*CPB, 256, 0, stream>>>(node_in, node_out, ew, cursor, csr);
  k_sumw   <<<nsb, 256, 0, stream>>>(csr, cursor, deg_w, logsum);
  k_prep   <<<1, 320, 0, stream>>>(qw, rel_W, rel_b, W1, b1, lin_W, rel6, qc, wcol);

  // layer 0 (specialized, no h input)
  k_layer0<<<nlb, 512, 0, stream>>>(rel6, cursor, csr, hidx, lin_W, lin_b,
                                    wcol, deg_w, logsum, h_a);

  float* hc = h_a;
  float* hn = h_b;
  for (int l = 1; l < 6; ++l){
    if (l == 5){
      k_dot<<<nb, 256, 0, stream>>>(hc, rel6, tdot);
      k_layer<true><<<nlb, 512, 0, stream>>>(hc, rel6, cursor, csr, hidx, tdot,
                                             lin_W, lin_b, deg_w, logsum,
                                             hn, out_pred,
                                             qc, W1, W2, b2, out_score, l);
    } else {
      k_layer<false><<<nlb, 512, 0, stream>>>(hc, rel6, cursor, csr, hidx, tdot,
                                              lin_W, lin_b, deg_w, logsum,
                                              hn, out_pred,
                                              qc, W1, W2, b2, out_score, l);
    }
    float* t1 = hc; hc = hn; hn = t1;
  }
}

// Round 21
// 424.449 us; speedup vs baseline: 1.1913x; 1.0397x over previous
//
#include <hip/hip_runtime.h>
#include <math.h>

#define NN 50000
#define EE 800000
#define DD 32
#define BSTR 64    // bucket stride (max degree ~45 at Poisson(16); +8 pad fits)
#define NPART 8    // node-range partitions, mapped to XCDs via blockIdx&7
#define CPB 128    // edge chunks per partition (grid = 8*128 = 1024 blocks)

typedef float v2f __attribute__((ext_vector_type(2)));

// ---------------- setup kernels ----------------

__global__ __launch_bounds__(256) void k_zero(float* p, int count){
  int i = blockIdx.x*256 + threadIdx.x;
  if (i < count) p[i] = 0.f;
}

// XCD-partitioned one-pass CSR build (R16-proven: cut write-amp 51->~12 MB).
__global__ __launch_bounds__(256) void k_fillcsr(const int* __restrict__ node_in,
                                                 const int* __restrict__ node_out,
                                                 const float* __restrict__ ew,
                                                 int* __restrict__ cursor,
                                                 int2* __restrict__ csr){
  int part  = blockIdx.x & (NPART-1);
  int group = blockIdx.x >> 3;
  const int per = (EE + CPB - 1) / CPB;   // 6250
  int e0 = group * per;
  int e1 = (e0 + per < EE) ? (e0 + per) : EE;
  unsigned lo = (unsigned)part * 6250u;
  unsigned hi = lo + 6250u;
  for (int e = e0 + threadIdx.x; e < e1; e += 256){
    unsigned o = (unsigned)node_out[e];
    if (o >= lo && o < hi){
      int pos = atomicAdd(&cursor[o], 1);
      int2 v; v.x = node_in[e]; v.y = __float_as_int(ew[e]);
      csr[o*BSTR + pos] = v;
    }
  }
}

// per-node sum(w): 8-lane group per node, coalesced bucket reads, shfl_xor
// reduce; zero the 8-entry pad tail in parallel; block logsum reduce.
__global__ __launch_bounds__(256) void k_sumw(int2* __restrict__ csr,
                                              const int* __restrict__ cursor,
                                              float* __restrict__ deg_w,
                                              float* __restrict__ logsum){
  __shared__ float sf[256];
  int t = threadIdx.x;
  int g = t >> 3, lane = t & 7;
  int n = blockIdx.x*32 + g;
  float s = 0.f;
  if (n < NN){
    int deg = cursor[n];
    int2* row = csr + n*BSTR;
    for (int i = lane; i < deg; i += 8) s += __int_as_float(row[i].y);
    s += __shfl_xor(s, 1);
    s += __shfl_xor(s, 2);
    s += __shfl_xor(s, 4);
    row[deg + lane] = make_int2(0, 0);   // 8 pads, one per lane
    if (lane == 0) deg_w[n] = s;
  }
  sf[t] = (n < NN && lane == 0) ? logf(s + 1.f) : 0.f;
  __syncthreads();
  for (int off = 128; off > 0; off >>= 1){
    if (t < off) sf[t] += sf[t+off];
    __syncthreads();
  }
  if (t == 0) atomicAdd(logsum, sf[0]);
}

// rel_input per layer (6x32), query-part of final MLP (64), and layer-0
// W column-sums over the h-part rows (boundary input is constant per node).
__global__ __launch_bounds__(320) void k_prep(const float* __restrict__ qw,
                                              const float* __restrict__ rel_W,
                                              const float* __restrict__ rel_b,
                                              const float* __restrict__ W1,
                                              const float* __restrict__ b1,
                                              const float* __restrict__ lin_W,
                                              float* __restrict__ rel6,
                                              float* __restrict__ qc,
                                              float* __restrict__ wcol){
  int t = threadIdx.x;
  if (t < 192){
    int l = t >> 5, j = t & 31;
    float s = rel_b[t];
    for (int d = 0; d < 32; ++d) s += qw[d] * rel_W[l*1024 + d*32 + j];
    rel6[t] = s;
  } else if (t < 256){
    int j = t - 192;
    float s = b1[j];
    for (int k = 0; k < 32; ++k) s += qw[k] * W1[(32+k)*64 + j];
    qc[j] = s;
  } else if (t < 288){
    int j = t - 256;
    float s = 0.f;
    for (int k = 0; k < 32; ++k) s += lin_W[k*32 + j];   // layer 0, h-part rows
    wcol[j] = s;
  }
}

// t[n] = dot(h[n], rel_layer5) for msg_score
__global__ __launch_bounds__(256) void k_dot(const float* __restrict__ h,
                                             const float* __restrict__ rel6,
                                             float* __restrict__ tdot){
  int n0 = blockIdx.x*256 + threadIdx.x;
  int n = (n0 < NN) ? n0 : NN-1;
  const float* relr = rel6 + 5*32;
  float s = 0.f;
  #pragma unroll
  for (int d = 0; d < 32; ++d) s += h[n*32 + d] * relr[d];
  if (n0 < NN) tdot[n0] = s;
}

// ---------------- layer 0 (specialized: boundary input) ----------------
__global__ __launch_bounds__(512, 6) void k_layer0(const float* __restrict__ rel6,
                                               const int* __restrict__ cursor,
                                               const int2* __restrict__ csr,
                                               const int* __restrict__ hidx,
                                               const float* __restrict__ lin_W,
                                               const float* __restrict__ lin_b,
                                               const float* __restrict__ wcol,
                                               const float* __restrict__ deg_w,
                                               const float* __restrict__ logsum,
                                               float* __restrict__ h_next){
  __shared__ float sh[128*65];
  int tid = threadIdx.x;
  int base = blockIdx.x * 64;
  int hv0 = *hidx;

  // ---- phase 1: scalar aggregation (csr scan only) ----
  {
    int nl   = tid >> 3;
    int quad = tid & 7;
    float4 r4 = ((const float4*)(rel6))[quad];   // layer 0
    int n0 = base + nl;
    int n = (n0 < NN) ? n0 : NN-1;
    int deg = cursor[n];
    int s0 = n*BSTR, s1 = s0 + deg;
    float S1=0.f, S2=0.f, M=-INFINITY, m=INFINITY;

#define ACCS(C) { \
    float w  = __int_as_float(C.y); \
    float hv = (C.x == hv0) ? 0.f : 100.f; \
    float wm = w * hv; \
    S1 += wm; S2 += wm * hv; \
    M = fmaxf(M, wm); m = fminf(m, wm); }

    int2 cA = csr[s0],   cB = csr[s0+1], cC = csr[s0+2], cD = csr[s0+3];
    int e = s0;
    for (; e + 4 <= s1; e += 4){
      int2 nA = csr[e+4], nB = csr[e+5], nC = csr[e+6], nD = csr[e+7];
      ACCS(cA) ACCS(cB) ACCS(cC) ACCS(cD)
      cA = nA; cB = nB; cC = nC; cD = nD;
    }
    if (e < s1){
      ACCS(cA)
      if (e + 1 < s1){
        ACCS(cB)
        if (e + 2 < s1) ACCS(cC)
      }
    }
#undef ACCS

    float bnd = (n == hv0) ? 0.f : 100.f;
    float cntf = (float)(deg + 1);
#define FIN(cc, rc) { \
    float mxv, mnv; \
    if (deg > 0){ \
      float em = (rc >= 0.f) ? rc*M : rc*m; \
      float en = (rc >= 0.f) ? rc*m : rc*M; \
      mxv = fmaxf(em, bnd); mnv = fminf(en, bnd); \
    } else { mxv = bnd; mnv = bnd; } \
    float meanv = (rc*S1 + bnd) / cntf; \
    float sq    = (rc*rc*S2 + bnd*bnd) / cntf; \
    float sdv   = sqrtf(fmaxf(sq - meanv*meanv, 1e-6f)); \
    int d = quad*4 + cc; \
    sh[(d*4+0)*65 + nl] = meanv; \
    sh[(d*4+1)*65 + nl] = mxv; \
    sh[(d*4+2)*65 + nl] = mnv; \
    sh[(d*4+3)*65 + nl] = sdv; }
    FIN(0, r4.x) FIN(1, r4.y) FIN(2, r4.z) FIN(3, r4.w)
#undef FIN
  }
  __syncthreads();

  // ---- phase 2: linear; x-part = bnd * wcol; 3-sum hoist of sc/iv ----
  {
    const float* Wl = lin_W;   // layer 0
    int lane = tid & 63;
    int j0 = __builtin_amdgcn_readfirstlane((tid >> 6) * 4);
    int n0 = base + lane;
    int n = (n0 < NN) ? n0 : NN-1;
    float mean = *logsum / (float)NN;
    float sc = logf(deg_w[n] + 1.f) / mean;
    float iv = 1.f / fmaxf(sc, 0.01f);
    float bndn = (n == hv0) ? 0.f : 100.f;
    v2f a01p={0,0}, a23p={0,0}, a01s={0,0}, a23s={0,0}, a01i={0,0}, a23i={0,0};

    for (int kp = 0; kp < 128; ++kp){
      float f = sh[kp*65 + lane];
      int d = kp >> 2, c = kp & 3;
      const v2f* w2 = (const v2f*)(Wl + (32 + d*12 + c*3)*32 + j0);
      v2f fv; fv[0]=f; fv[1]=f;
      a01p += fv*w2[0];  a23p += fv*w2[1];
      a01s += fv*w2[16]; a23s += fv*w2[17];
      a01i += fv*w2[32]; a23i += fv*w2[33];
    }
    v2f sc2; sc2[0]=sc; sc2[1]=sc;
    v2f iv2; iv2[0]=iv; iv2[1]=iv;
    v2f a01 = a01p + sc2*a01s + iv2*a01i;
    v2f a23 = a23p + sc2*a23s + iv2*a23i;
    a01[0] += lin_b[j0+0] + bndn*wcol[j0+0];
    a01[1] += lin_b[j0+1] + bndn*wcol[j0+1];
    a23[0] += lin_b[j0+2] + bndn*wcol[j0+2];
    a23[1] += lin_b[j0+3] + bndn*wcol[j0+3];

    if (n0 < NN){
      float vs[4] = { a01[0], a01[1], a23[0], a23[1] };
      #pragma unroll
      for (int j = 0; j < 4; ++j)
        h_next[n0*32 + j0 + j] = fmaxf(vs[j], 0.f);
    }
  }
}

// ---------------- fused per-layer kernel (layers 1..5) ----------------
// R18-proven structure: unroll-4 issue-then-wait phase 1 (packed v2f
// accumulate for S1/S2), 3-sum-hoisted packed-fp32 j-split phase 2 (sc/iv
// applied once at the end -- saves ~40% of phase-2 instructions). PRED
// (l=5): predecessor tracking in phase 1, final MLP fused in the epilogue.
template<bool PRED>
__global__ __launch_bounds__(512, 6) void k_layer(const float* __restrict__ h,
                                               const float* __restrict__ rel6,
                                               const int* __restrict__ cursor,
                                               const int2* __restrict__ csr,
                                               const int* __restrict__ hidx,
                                               const float* __restrict__ tdot,
                                               const float* __restrict__ lin_W,
                                               const float* __restrict__ lin_b,
                                               const float* __restrict__ deg_w,
                                               const float* __restrict__ logsum,
                                               float* __restrict__ h_next,
                                               float* __restrict__ pred_out,
                                               const float* __restrict__ qc,
                                               const float* __restrict__ W1,
                                               const float* __restrict__ W2,
                                               const float* __restrict__ b2,
                                               float* __restrict__ out_score,
                                               int l){
  __shared__ float sh[128*65];
  int tid = threadIdx.x;
  int base = blockIdx.x * 64;
  int hv0 = *hidx;

  // ---- phase 1: aggregation (one 8-lane group per node, unroll-4) ----
  {
    int nl   = tid >> 3;
    int quad = tid & 7;
    float4 r4 = ((const float4*)(rel6 + l*32))[quad];
    int n0 = base + nl;
    bool valid = n0 < NN;
    int n = valid ? n0 : NN-1;
    int deg = cursor[n];
    int s0 = n*BSTR, s1 = s0 + deg;
    v2f S1xy={0,0}, S1zw={0,0}, S2xy={0,0}, S2zw={0,0};
    float M0=-INFINITY,M1=-INFINITY,M2=-INFINITY,M3=-INFINITY;
    float m0=INFINITY,m1=INFINITY,m2=INFINITY,m3=INFINITY;
    float best=-INFINITY; int bi=NN;

#define ACC1(C, A, T) { \
    float w = __int_as_float(C.y); \
    v2f wv; wv[0]=w; wv[1]=w; \
    v2f axy; axy[0]=A.x; axy[1]=A.y; \
    v2f azw; azw[0]=A.z; azw[1]=A.w; \
    v2f pxy = wv*axy, pzw = wv*azw; \
    S1xy += pxy; S1zw += pzw; \
    S2xy += pxy*axy; S2zw += pzw*azw; \
    M0=fmaxf(M0,pxy[0]); M1=fmaxf(M1,pxy[1]); M2=fmaxf(M2,pzw[0]); M3=fmaxf(M3,pzw[1]); \
    m0=fminf(m0,pxy[0]); m1=fminf(m1,pxy[1]); m2=fminf(m2,pzw[0]); m3=fminf(m3,pzw[1]); \
    if (PRED){ \
      float sv = w*T; \
      if (sv > best){ best = sv; bi = C.x; } \
      else if (sv == best && C.x < bi) bi = C.x; \
    } }

    int2 cA = csr[s0],   cB = csr[s0+1], cC = csr[s0+2], cD = csr[s0+3];
    int e = s0;
    for (; e + 4 <= s1; e += 4){
      float4 a  = ((const float4*)(h + cA.x*32))[quad];
      float4 b  = ((const float4*)(h + cB.x*32))[quad];
      float4 c4 = ((const float4*)(h + cC.x*32))[quad];
      float4 d4 = ((const float4*)(h + cD.x*32))[quad];
      float tA=0.f, tB=0.f, tC=0.f, tD=0.f;
      if (PRED){ tA = tdot[cA.x]; tB = tdot[cB.x]; tC = tdot[cC.x]; tD = tdot[cD.x]; }
      int2 nA = csr[e+4], nB = csr[e+5], nC = csr[e+6], nD = csr[e+7];
      ACC1(cA, a, tA)
      ACC1(cB, b, tB)
      ACC1(cC, c4, tC)
      ACC1(cD, d4, tD)
      cA = nA; cB = nB; cC = nC; cD = nD;
    }
    if (e < s1){
      float4 a = ((const float4*)(h + cA.x*32))[quad];
      float tA = 0.f; if (PRED) tA = tdot[cA.x];
      ACC1(cA, a, tA)
      if (e + 1 < s1){
        float4 b = ((const float4*)(h + cB.x*32))[quad];
        float tB = 0.f; if (PRED) tB = tdot[cB.x];
        ACC1(cB, b, tB)
        if (e + 2 < s1){
          float4 c4 = ((const float4*)(h + cC.x*32))[quad];
          float tC = 0.f; if (PRED) tC = tdot[cC.x];
          ACC1(cC, c4, tC)
        }
      }
    }
#undef ACC1

    float bnd = (n == hv0) ? 0.f : 100.f;
    float cntf = (float)(deg + 1);
#define FIN(cc, rc, S1c, S2c, Mc, mc) { \
    float mxv, mnv; \
    if (deg > 0){ \
      float em = (rc >= 0.f) ? rc*Mc : rc*mc; \
      float en = (rc >= 0.f) ? rc*mc : rc*Mc; \
      mxv = fmaxf(em, bnd); mnv = fminf(en, bnd); \
    } else { mxv = bnd; mnv = bnd; } \
    float meanv = (rc*S1c + bnd) / cntf; \
    float sq    = (rc*rc*S2c + bnd*bnd) / cntf; \
    float sdv   = sqrtf(fmaxf(sq - meanv*meanv, 1e-6f)); \
    int d = quad*4 + cc; \
    sh[(d*4+0)*65 + nl] = meanv; \
    sh[(d*4+1)*65 + nl] = mxv; \
    sh[(d*4+2)*65 + nl] = mnv; \
    sh[(d*4+3)*65 + nl] = sdv; }
    FIN(0, r4.x, S1xy[0], S2xy[0], M0, m0)
    FIN(1, r4.y, S1xy[1], S2xy[1], M1, m1)
    FIN(2, r4.z, S1zw[0], S2zw[0], M2, m2)
    FIN(3, r4.w, S1zw[1], S2zw[1], M3, m3)
#undef FIN
    if (PRED && valid && quad == 0){
      float ss = (n == hv0) ? 0.f : 3200.f;   // boundary self-loop row sum, w=1
      if (ss > best){ best = ss; bi = n; }
      else if (ss == best && n < bi) bi = n;
      pred_out[n] = (float)bi;
    }
  }
  __syncthreads();

  // ---- phase 2: linear (8 waves, wave w -> j0 = w*4; node = lane) ----
  // 3-sum hoist: acc = P + sc*S + iv*I applied once at the end.
  {
    const float* Wl = lin_W + (size_t)l * 13312;
    int lane = tid & 63;
    int j0 = __builtin_amdgcn_readfirstlane((tid >> 6) * 4);
    int n0 = base + lane;
    int n = (n0 < NN) ? n0 : NN-1;
    float mean = *logsum / (float)NN;
    float sc = logf(deg_w[n] + 1.f) / mean;
    float iv = 1.f / fmaxf(sc, 0.01f);
    const float4* hr = (const float4*)(h + (size_t)n*32);
    float4 x0=hr[0],x1=hr[1],x2=hr[2],x3=hr[3],x4=hr[4],x5=hr[5],x6=hr[6],x7=hr[7];
    v2f a01p={0,0}, a23p={0,0}, a01s={0,0}, a23s={0,0}, a01i={0,0}, a23i={0,0};

#define KONE(XV, K) { \
    v2f xv2; xv2[0] = XV; xv2[1] = XV; \
    const v2f* wr2 = (const v2f*)(Wl + (K)*32 + j0); \
    a01p += xv2 * wr2[0]; \
    a23p += xv2 * wr2[1]; }
#define KQ(X, KB) KONE(X.x, KB+0) KONE(X.y, KB+1) KONE(X.z, KB+2) KONE(X.w, KB+3)
    KQ(x0, 0) KQ(x1, 4) KQ(x2, 8) KQ(x3, 12)
    KQ(x4, 16) KQ(x5, 20) KQ(x6, 24) KQ(x7, 28)
#undef KQ
#undef KONE

    for (int kp = 0; kp < 128; ++kp){
      float f = sh[kp*65 + lane];
      int d = kp >> 2, c = kp & 3;
      const v2f* w2 = (const v2f*)(Wl + (32 + d*12 + c*3)*32 + j0);
      v2f fv; fv[0]=f; fv[1]=f;
      a01p += fv*w2[0];  a23p += fv*w2[1];
      a01s += fv*w2[16]; a23s += fv*w2[17];
      a01i += fv*w2[32]; a23i += fv*w2[33];
    }
    v2f sc2; sc2[0]=sc; sc2[1]=sc;
    v2f iv2; iv2[0]=iv; iv2[1]=iv;
    v2f a01 = a01p + sc2*a01s + iv2*a01i;
    v2f a23 = a23p + sc2*a23s + iv2*a23i;
    a01[0] += lin_b[l*32 + j0 + 0];
    a01[1] += lin_b[l*32 + j0 + 1];
    a23[0] += lin_b[l*32 + j0 + 2];
    a23[1] += lin_b[l*32 + j0 + 3];

    float v0r = fmaxf(a01[0], 0.f), v1r = fmaxf(a01[1], 0.f);
    float v2r = fmaxf(a23[0], 0.f), v3r = fmaxf(a23[1], 0.f);

    if (!PRED){
      if (n0 < NN){
        h_next[n0*32 + j0 + 0] = v0r;
        h_next[n0*32 + j0 + 1] = v1r;
        h_next[n0*32 + j0 + 2] = v2r;
        h_next[n0*32 + j0 + 3] = v3r;
      }
    } else {
      // ---- fused final MLP (l=5): h6 never leaves the block ----
      __syncthreads();                    // all phase-2 sh reads complete
      sh[(j0+0)*65 + lane] = v0r;         // stage h6 rows 0..31
      sh[(j0+1)*65 + lane] = v1r;
      sh[(j0+2)*65 + lane] = v2r;
      sh[(j0+3)*65 + lane] = v3r;
      __syncthreads();
      int node = tid & 63;
      int grp  = __builtin_amdgcn_readfirstlane(tid >> 6);   // 0..7
      int jm = grp*8;                     // wave-uniform -> W1 s_loads
      v2f b0, b1v, b2v, b3;
      b0[0]=qc[jm+0]; b0[1]=qc[jm+1]; b1v[0]=qc[jm+2]; b1v[1]=qc[jm+3];
      b2v[0]=qc[jm+4]; b2v[1]=qc[jm+5]; b3[0]=qc[jm+6]; b3[1]=qc[jm+7];
      for (int k = 0; k < 32; ++k){
        float xv = sh[k*65 + node];
        const v2f* wr = (const v2f*)(W1 + k*64 + jm);
        v2f xv2; xv2[0]=xv; xv2[1]=xv;
        b0 += xv2*wr[0]; b1v += xv2*wr[1]; b2v += xv2*wr[2]; b3 += xv2*wr[3];
      }
      float part = fmaxf(b0[0],0.f)*W2[jm+0] + fmaxf(b0[1],0.f)*W2[jm+1]
                 + fmaxf(b1v[0],0.f)*W2[jm+2] + fmaxf(b1v[1],0.f)*W2[jm+3]
                 + fmaxf(b2v[0],0.f)*W2[jm+4] + fmaxf(b2v[1],0.f)*W2[jm+5]
                 + fmaxf(b3[0],0.f)*W2[jm+6] + fmaxf(b3[1],0.f)*W2[jm+7];
      sh[2080 + node*9 + grp] = part;     // past the 32 staged rows (2080)
      __syncthreads();
      if (tid < 64){
        float s = b2[0];
        #pragma unroll
        for (int g = 0; g < 8; ++g) s += sh[2080 + tid*9 + g];
        if (base + tid < NN) out_score[base + tid] = s;
      }
    }
  }
}

// ---------------- host launch ----------------
extern "C" void kernel_launch(void* const* d_in, const int* in_sizes, int n_in,
                              void* d_out, int out_size, void* d_ws, size_t ws_size,
                              hipStream_t stream){
  const int*   node_in  = (const int*)d_in[0];
  const int*   node_out = (const int*)d_in[1];
  const float* ew       = (const float*)d_in[2];
  const int*   hidx     = (const int*)d_in[3];
  const float* qw       = (const float*)d_in[4];
  const float* rel_W    = (const float*)d_in[5];
  const float* rel_b    = (const float*)d_in[6];
  const float* lin_W    = (const float*)d_in[7];
  const float* lin_b    = (const float*)d_in[8];
  const float* W1       = (const float*)d_in[9];
  const float* b1       = (const float*)d_in[10];
  const float* W2       = (const float*)d_in[11];
  const float* b2       = (const float*)d_in[12];
  float* out_score = (float*)d_out;
  float* out_pred  = out_score + NN;

  char* w = (char*)d_ws;
  size_t off = 0;
  auto take = [&](size_t bytes)->char*{
    char* p = w + off;
    off = (off + bytes + 255) & ~(size_t)255;
    return p;
  };
  size_t bucket_elems = (size_t)NN * BSTR;            // int2 entries
  int2*  csr      = (int2*)take(bucket_elems*8);
  // contiguous zero block: cursor | deg_w | logsum
  char*  zb       = take((size_t)NN*4 + (size_t)NN*4 + 256);
  int*   cursor   = (int*)zb;
  float* deg_w    = (float*)(cursor + NN);
  float* logsum   = (float*)(deg_w + NN);
  int zc = NN + NN + 64;

  float* rel6      = (float*)take(192*4);
  float* qc        = (float*)take(64*4);
  float* wcol      = (float*)take(32*4);
  float* tdot      = (float*)take((size_t)NN*4);
  float* h_a       = (float*)take((size_t)NN*32*4);
  float* h_b       = (float*)take((size_t)NN*32*4);

  int nb  = (NN + 255) / 256;   // 196
  int nsb = (NN + 31) / 32;     // 1563 (k_sumw: 32 nodes/block)
  int nlb = (NN + 63) / 64;     // 782
  k_zero   <<<(zc+255)/256, 256, 0, stream>>>((float*)zb, zc);
  k_fillcsr<<<NPART*CPB, 256, 0, stream>>>(node_in, node_out, ew, cursor, csr);
  k_sumw   <<<nsb, 256, 0, stream>>>(csr, cursor, deg_w, logsum);
  k_prep   <<<1, 320, 0, stream>>>(qw, rel_W, rel_b, W1, b1, lin_W, rel6, qc, wcol);

  // layer 0 (specialized, no h input)
  k_layer0<<<nlb, 512, 0, stream>>>(rel6, cursor, csr, hidx, lin_W, lin_b,
                                    wcol, deg_w, logsum, h_a);

  float* hc = h_a;
  float* hn = h_b;
  for (int l = 1; l < 6; ++l){
    if (l == 5){
      k_dot<<<nb, 256, 0, stream>>>(hc, rel6, tdot);
      k_layer<true><<<nlb, 512, 0, stream>>>(hc, rel6, cursor, csr, hidx, tdot,
                                             lin_W, lin_b, deg_w, logsum,
                                             hn, out_pred,
                                             qc, W1, W2, b2, out_score, l);
    } else {
      k_layer<false><<<nlb, 512, 0, stream>>>(hc, rel6, cursor, csr, hidx, tdot,
                                              lin_W, lin_b, deg_w, logsum,
                                              hn, out_pred,
                                              qc, W1, W2, b2, out_score, l);
    }
    float* t1 = hc; hc = hn; hn = t1;
  }
}